// Round 4
// baseline (281.888 us; speedup 1.0000x reference)
//
#include <hip/hip_runtime.h>
#include <stdint.h>

// Pipeline: detect dtype -> cast inputs to bf16 -> transpose weights ->
//   GEMM1(x @ w_attn^T, scatter Q*scale / K+rel / V^T) -> flash attention ->
//   GEMM2 (+b_proj) -> out (dtype matches detected input dtype)
//
// Workspace layout (bytes):
//   flag (int)            @ 0
//   wTa  [2304][768] bf16 @ 4096        (3538944)
//   wTp  [768][768]  bf16 @ 3543040     (1179648)
//   x_bf [8192][768] bf16 @ 4722688     (12582912)  -- later reused as att
//   rel_bf [2047][64]     @ 17305600    (262016)
//   ba_bf [2304]          @ 17567616    (4608)
//   bp_bf [768]           @ 17572224    (1536)
//   Q_ws [b][h][t][64]    @ 17573760    (12582912)  (scale folded)
//   K_ws [b][h][t][64]    @ 30156672    (12582912)  (rel folded)
//   V_ws [b][h][64][t]    @ 42739584    (12582912)  (transposed)
//   att  [b*t][768]       @ 4722688     (aliases x_bf; safe: stream-ordered)

typedef __attribute__((ext_vector_type(8))) short short8;
typedef __attribute__((ext_vector_type(4))) float f32x4;
typedef __attribute__((ext_vector_type(4))) unsigned short ushort4v;

#define DEV static __device__ __forceinline__

DEV float bf2f(unsigned short u) {
    union { unsigned int u; float f; } v; v.u = ((unsigned int)u) << 16; return v.f;
}
DEV unsigned short f2bf(float f) {
    union { float f; unsigned int u; } v; v.f = f;
    unsigned int u = v.u;
    return (unsigned short)((u + 0x7fffu + ((u >> 16) & 1u)) >> 16);
}

typedef const __attribute__((address_space(1))) void* gas_ptr;
typedef __attribute__((address_space(3))) void* las_ptr;
DEV void glds16(const void* g, void* l) {
    __builtin_amdgcn_global_load_lds((gas_ptr)g, (las_ptr)l, 16, 0, 0);
}

// ---------------- dtype detector ----------------
__global__ void detect_dtype(const unsigned int* __restrict__ w, int* __restrict__ flag) {
    __shared__ int cnt;
    if (threadIdx.x == 0) cnt = 0;
    __syncthreads();
    int c = 0;
    for (int i = threadIdx.x; i < 8192; i += 256) {
        unsigned int b1 = (w[i] >> 8) & 0x7F;
        c += (b1 >= 0x38 && b1 <= 0x3E) ? 1 : 0;
    }
    atomicAdd(&cnt, c);
    __syncthreads();
    if (threadIdx.x == 0) *flag = (cnt > 4096) ? 1 : 0;  // 1 = bf16 inputs
}

// ---------------- casts ----------------
__global__ __launch_bounds__(256) void cast_x(
    const void* __restrict__ x, unsigned short* __restrict__ xo,
    const int* __restrict__ flag)
{
    int i = (blockIdx.x * 256 + threadIdx.x) * 4;
    if (*flag) {
        *(ushort4v*)(xo + i) = *(const ushort4v*)((const unsigned short*)x + i);
    } else {
        f32x4 v = *(const f32x4*)((const float*)x + i);
        ushort4v o;
#pragma unroll
        for (int j = 0; j < 4; ++j) o[j] = f2bf(v[j]);
        *(ushort4v*)(xo + i) = o;
    }
}

__global__ __launch_bounds__(256) void cast_small(
    const void* __restrict__ rel, const void* __restrict__ ba, const void* __restrict__ bp,
    unsigned short* __restrict__ rel_o, unsigned short* __restrict__ ba_o,
    unsigned short* __restrict__ bp_o, const int* __restrict__ flag)
{
    int i = blockIdx.x * 256 + threadIdx.x;
    if (i >= 134080) return;
    int isbf = *flag;
    const void* src; unsigned short* dst; int off;
    if (i < 131008)      { src = rel; dst = rel_o; off = i; }
    else if (i < 133312) { src = ba;  dst = ba_o;  off = i - 131008; }
    else                 { src = bp;  dst = bp_o;  off = i - 133312; }
    dst[off] = isbf ? ((const unsigned short*)src)[off]
                    : f2bf(((const float*)src)[off]);
}

// ---------------- weight transpose (either dtype in, bf16 out), 64x64 tiles ----
__global__ __launch_bounds__(256) void transpose_w(
    const void* __restrict__ in, unsigned short* __restrict__ out,
    int R, int C, const int* __restrict__ flag)
{
    __shared__ unsigned short tile[64][66];
    const int t = threadIdx.x;
    const int cb = blockIdx.x * 64;
    const int rb = blockIdx.y * 64;
    if (*flag) {
        const unsigned short* inp = (const unsigned short*)in;
        const int c8 = (t & 7) * 8;
        const int r = t >> 3;
#pragma unroll
        for (int p = 0; p < 2; ++p) {
            int rr = r + p * 32;
            short8 v = *(const short8*)(inp + (size_t)(rb + rr) * C + cb + c8);
#pragma unroll
            for (int i = 0; i < 8; ++i) tile[rr][c8 + i] = (unsigned short)v[i];
        }
    } else {
        const float* inp = (const float*)in;
        const int c4 = (t & 15) * 4;
        const int r = t >> 4;
#pragma unroll
        for (int p = 0; p < 4; ++p) {
            int rr = r + p * 16;
            f32x4 v = *(const f32x4*)(inp + (size_t)(rb + rr) * C + cb + c4);
#pragma unroll
            for (int i = 0; i < 4; ++i) tile[rr][c4 + i] = f2bf(v[i]);
        }
    }
    __syncthreads();
    {
        const int c8 = (t & 7) * 8;
        const int r = t >> 3;
#pragma unroll
        for (int p = 0; p < 2; ++p) {
            int oc = r + p * 32;
            short8 v;
#pragma unroll
            for (int i = 0; i < 8; ++i) v[i] = (short)tile[c8 + i][oc];
            *(short8*)(out + (size_t)(cb + oc) * R + rb + c8) = v;
        }
    }
}

// ---------------- GEMM skeleton: 128x128 tile, BK=32, 4 waves ----------------
#define GEMM_PROLOG(A_, Bt_)                                                     \
    __shared__ __align__(16) unsigned short Abuf[128 * 32];                      \
    __shared__ __align__(16) unsigned short Bbuf[128 * 32];                      \
    const int t = threadIdx.x;                                                   \
    const int wave = t >> 6, lane = t & 63;                                      \
    const int lo = lane & 15, hi = lane >> 4;                                    \
    const int wr = wave >> 1, wc = wave & 1;                                     \
    const int bm = blockIdx.x * 128;                                             \
    const int bn = blockIdx.y * 128;                                             \
    int L0 = t << 4, L1 = (t + 256) << 4;                                        \
    int S0 = L0 ^ (((L0 >> 7) & 3) << 4);                                        \
    int S1 = L1 ^ (((L1 >> 7) & 3) << 4);                                        \
    int r0 = S0 >> 6, o0 = (S0 & 63) >> 1;                                       \
    int r1 = S1 >> 6, o1 = (S1 & 63) >> 1;                                       \
    const unsigned short* Ab = (A_) + (size_t)bm * 768;                          \
    const unsigned short* Bb = (Bt_) + (size_t)bn * 768;                         \
    char* lA0 = (char*)Abuf + ((wave * 64) << 4);                                \
    char* lA1 = (char*)Abuf + ((256 + wave * 64) << 4);                          \
    char* lB0 = (char*)Bbuf + ((wave * 64) << 4);                                \
    char* lB1 = (char*)Bbuf + ((256 + wave * 64) << 4);                          \
    const char* ap[4]; const char* bp_[4];                                       \
    _Pragma("unroll")                                                            \
    for (int m = 0; m < 4; ++m) {                                                \
        int Pa = ((wr * 64 + m * 16 + lo) << 6) + (hi << 4);                     \
        ap[m] = (const char*)Abuf + (Pa ^ (((Pa >> 7) & 3) << 4));               \
        int Pb = ((wc * 64 + m * 16 + lo) << 6) + (hi << 4);                     \
        bp_[m] = (const char*)Bbuf + (Pb ^ (((Pb >> 7) & 3) << 4));              \
    }                                                                            \
    f32x4 acc[4][4];                                                             \
    _Pragma("unroll")                                                            \
    for (int m = 0; m < 4; ++m)                                                  \
        _Pragma("unroll")                                                        \
        for (int n = 0; n < 4; ++n) acc[m][n] = (f32x4){0.f, 0.f, 0.f, 0.f};     \
    for (int k0 = 0; k0 < 768; k0 += 32) {                                       \
        glds16(Ab + (size_t)r0 * 768 + k0 + o0, lA0);                            \
        glds16(Ab + (size_t)r1 * 768 + k0 + o1, lA1);                            \
        glds16(Bb + (size_t)r0 * 768 + k0 + o0, lB0);                            \
        glds16(Bb + (size_t)r1 * 768 + k0 + o1, lB1);                            \
        __syncthreads();                                                         \
        short8 af[4], bfv[4];                                                    \
        _Pragma("unroll")                                                        \
        for (int m = 0; m < 4; ++m) af[m] = *(const short8*)ap[m];               \
        _Pragma("unroll")                                                        \
        for (int n = 0; n < 4; ++n) bfv[n] = *(const short8*)bp_[n];             \
        _Pragma("unroll")                                                        \
        for (int m = 0; m < 4; ++m)                                              \
            _Pragma("unroll")                                                    \
            for (int n = 0; n < 4; ++n)                                          \
                acc[m][n] = __builtin_amdgcn_mfma_f32_16x16x32_bf16(             \
                    af[m], bfv[n], acc[m][n], 0, 0, 0);                          \
        __syncthreads();                                                         \
    }

// GEMM1: epilogue scatters q (scaled), k (+rel), v (transposed)
__global__ __launch_bounds__(256) void gemm_qkv(
    const unsigned short* __restrict__ A,
    const unsigned short* __restrict__ Bt,
    const unsigned short* __restrict__ bias,
    const unsigned short* __restrict__ rel,
    unsigned short* __restrict__ q_ws,
    unsigned short* __restrict__ k_ws,
    unsigned short* __restrict__ v_ws)
{
    GEMM_PROLOG(A, Bt)
    const int gm0 = bm + wr * 64 + hi * 4;
#pragma unroll
    for (int m = 0; m < 4; ++m) {
        int gm = gm0 + m * 16;
        int b_ = gm >> 10;
        int tt = gm & 1023;
#pragma unroll
        for (int n = 0; n < 4; ++n) {
            int col = bn + wc * 64 + n * 16 + lo;
            float bs = bf2f(bias[col]);
            if (col < 768) {
                int h = col >> 6, d = col & 63;
                size_t base = (((size_t)b_ * 12 + h) * 1024 + tt) * 64 + d;
#pragma unroll
                for (int j = 0; j < 4; ++j)
                    q_ws[base + (size_t)j * 64] = f2bf((acc[m][n][j] + bs) * 0.125f);
            } else if (col < 1536) {
                int h = (col - 768) >> 6, d = col & 63;
                size_t base = (((size_t)b_ * 12 + h) * 1024 + tt) * 64 + d;
#pragma unroll
                for (int j = 0; j < 4; ++j) {
                    int trow = tt + j;
                    float rv = (trow > 0) ? bf2f(rel[(size_t)(trow - 1) * 64 + d]) : 0.f;
                    k_ws[base + (size_t)j * 64] = f2bf(acc[m][n][j] + bs + rv);
                }
            } else {
                int h = (col - 1536) >> 6, d = col & 63;
                size_t vb = (((size_t)b_ * 12 + h) * 64 + d) * 1024 + tt;
                ushort4v pk;
#pragma unroll
                for (int j = 0; j < 4; ++j) pk[j] = f2bf(acc[m][n][j] + bs);
                *(ushort4v*)(v_ws + vb) = pk;
            }
        }
    }
}

// GEMM2: att @ wT_proj + b_proj -> out (dtype per flag)
__global__ __launch_bounds__(256) void gemm_proj(
    const unsigned short* __restrict__ A,
    const unsigned short* __restrict__ Bt,
    const unsigned short* __restrict__ bias,
    const int* __restrict__ flag,
    void* __restrict__ outv)
{
    GEMM_PROLOG(A, Bt)
    const int isbf = *flag;
    const int gm0 = bm + wr * 64 + hi * 4;
#pragma unroll
    for (int m = 0; m < 4; ++m) {
        int gm = gm0 + m * 16;
#pragma unroll
        for (int n = 0; n < 4; ++n) {
            int col = bn + wc * 64 + n * 16 + lo;
            float bs = bf2f(bias[col]);
#pragma unroll
            for (int j = 0; j < 4; ++j) {
                float v = acc[m][n][j] + bs;
                if (isbf)
                    ((unsigned short*)outv)[(size_t)(gm + j) * 768 + col] = f2bf(v);
                else
                    ((float*)outv)[(size_t)(gm + j) * 768 + col] = v;
            }
        }
    }
}

// ---------------- flash attention (v3: wave-independent, no LDS staging) ------
// K/V per head = 256KB -> L2-resident; load MFMA fragments straight from global.
// No __syncthreads anywhere: 4 waves per block work on independent 16-row
// q-tiles. Only wave-private P round-trip uses LDS (2KB/wave, swizzled).
// Grid 1536 1-D, XCD-partitioned: xcd = gid&7 owns heads 12*xcd..12*xcd+11
// (3MB K/V per XCD L2); qt descending (heavy-first) within each XCD.
__global__ __launch_bounds__(256) void attn_fused(
    const unsigned short* __restrict__ q_ws,
    const unsigned short* __restrict__ k_ws,
    const unsigned short* __restrict__ v_ws,
    unsigned short* __restrict__ att)
{
    __shared__ __align__(16) unsigned short Pbuf[4][16 * 64];
    const int t = threadIdx.x;
    const int wave = t >> 6, lane = t & 63;
    const int lo = lane & 15, hi = lane >> 4;
    const int gid = blockIdx.x;
    const int xcd = gid & 7;
    const int c = gid >> 3;            // 0..191
    const int bh = xcd * 12 + (c % 12);
    const int qt = 15 - (c / 12);
    const int b_ = bh / 12, h = bh % 12;
    const size_t base = (size_t)bh * (1024 * 64);
    const int q0w = qt * 64 + wave * 16;

    const unsigned short* Kb = k_ws + base;
    const unsigned short* Vb = v_ws + base;

    short8 qf[2];
#pragma unroll
    for (int kc = 0; kc < 2; ++kc)
        qf[kc] = *(const short8*)(q_ws + base +
            (size_t)(q0w + lo) * 64 + kc * 32 + hi * 8);

    // wave-private P buffer, 128B rows, XOR swizzle ^((row&7)<<4)
    char* pb = (char*)&Pbuf[wave][0];
    int poffR[2];
#pragma unroll
    for (int kc = 0; kc < 2; ++kc) {
        int P = (lo << 7) + (kc << 6) + (hi << 4);
        poffR[kc] = P ^ (((P >> 7) & 7) << 4);
    }
    int poffW[4][4];
#pragma unroll
    for (int nt = 0; nt < 4; ++nt)
#pragma unroll
        for (int j = 0; j < 4; ++j) {
            int P = ((hi * 4 + j) << 7) + ((nt * 16 + lo) << 1);
            poffW[nt][j] = P ^ (((P >> 7) & 7) << 4);
        }

    f32x4 o[4];
    float mrun[4], lrun[4];
#pragma unroll
    for (int nt = 0; nt < 4; ++nt) o[nt] = (f32x4){0.f, 0.f, 0.f, 0.f};
#pragma unroll
    for (int j = 0; j < 4; ++j) { mrun[j] = -1e30f; lrun[j] = 0.f; }

    const int nkt = qt + 1;
    for (int kt = 0; kt < nkt; ++kt) {
        const int kv0 = kt * 64;
        // K fragments straight from global (L2-hit)
        short8 kf[4][2];
#pragma unroll
        for (int nt = 0; nt < 4; ++nt)
#pragma unroll
            for (int kc = 0; kc < 2; ++kc)
                kf[nt][kc] = *(const short8*)(Kb +
                    (size_t)(kv0 + nt * 16 + lo) * 64 + kc * 32 + hi * 8);
        f32x4 sc[4];
        __builtin_amdgcn_s_setprio(1);
#pragma unroll
        for (int nt = 0; nt < 4; ++nt) {
            f32x4 z = (f32x4){0.f, 0.f, 0.f, 0.f};
            z = __builtin_amdgcn_mfma_f32_16x16x32_bf16(qf[0], kf[nt][0], z, 0, 0, 0);
            z = __builtin_amdgcn_mfma_f32_16x16x32_bf16(qf[1], kf[nt][1], z, 0, 0, 0);
            sc[nt] = z;
        }
        __builtin_amdgcn_s_setprio(0);
        if (kv0 + 63 > q0w) {
#pragma unroll
            for (int nt = 0; nt < 4; ++nt)
#pragma unroll
                for (int j = 0; j < 4; ++j) {
                    int qr = q0w + hi * 4 + j;
                    int kc_ = kv0 + nt * 16 + lo;
                    if (kc_ > qr) sc[nt][j] = -1e30f;
                }
        }
        // online softmax with defer-max (skip rescale when max growth <= 8)
        float mx[4];
        int need = 0;
#pragma unroll
        for (int j = 0; j < 4; ++j) {
            float m0 = fmaxf(fmaxf(sc[0][j], sc[1][j]), fmaxf(sc[2][j], sc[3][j]));
            m0 = fmaxf(m0, __shfl_xor(m0, 1));
            m0 = fmaxf(m0, __shfl_xor(m0, 2));
            m0 = fmaxf(m0, __shfl_xor(m0, 4));
            m0 = fmaxf(m0, __shfl_xor(m0, 8));
            mx[j] = m0;
            need |= (m0 > mrun[j] + 8.f) ? 1 : 0;
        }
        if (__any(need)) {
#pragma unroll
            for (int j = 0; j < 4; ++j) {
                float nm = fmaxf(mrun[j], mx[j]);
                float corr = __expf(mrun[j] - nm);
                mrun[j] = nm;
                lrun[j] *= corr;
#pragma unroll
                for (int nt = 0; nt < 4; ++nt) o[nt][j] *= corr;
            }
        }
#pragma unroll
        for (int j = 0; j < 4; ++j) {
            float rs = 0.f;
#pragma unroll
            for (int nt = 0; nt < 4; ++nt) {
                float p = __expf(sc[nt][j] - mrun[j]);
                sc[nt][j] = p;
                rs += p;
            }
            rs += __shfl_xor(rs, 1);
            rs += __shfl_xor(rs, 2);
            rs += __shfl_xor(rs, 4);
            rs += __shfl_xor(rs, 8);
            lrun[j] += rs;
        }
        // V fragments (issued before P round-trip so L2 latency hides under it)
        short8 vf[4][2];
#pragma unroll
        for (int nt = 0; nt < 4; ++nt)
#pragma unroll
            for (int kc2 = 0; kc2 < 2; ++kc2)
                vf[nt][kc2] = *(const short8*)(Vb +
                    (size_t)(nt * 16 + lo) * 1024 + kv0 + kc2 * 32 + hi * 8);
        // P -> LDS (wave-private, no barrier)
#pragma unroll
        for (int nt = 0; nt < 4; ++nt)
#pragma unroll
            for (int j = 0; j < 4; ++j)
                *(unsigned short*)(pb + poffW[nt][j]) = f2bf(sc[nt][j]);
        // PV
#pragma unroll
        for (int kc2 = 0; kc2 < 2; ++kc2) {
            short8 pf = *(const short8*)(pb + poffR[kc2]);
            __builtin_amdgcn_s_setprio(1);
#pragma unroll
            for (int nt = 0; nt < 4; ++nt)
                o[nt] = __builtin_amdgcn_mfma_f32_16x16x32_bf16(pf, vf[nt][kc2], o[nt], 0, 0, 0);
            __builtin_amdgcn_s_setprio(0);
        }
    }
#pragma unroll
    for (int j = 0; j < 4; ++j) {
        int tt = q0w + hi * 4 + j;
        float inv = 1.f / lrun[j];
#pragma unroll
        for (int nt = 0; nt < 4; ++nt)
            att[((size_t)(b_ * 1024 + tt)) * 768 + h * 64 + nt * 16 + lo] =
                f2bf(o[nt][j] * inv);
    }
}

extern "C" void kernel_launch(void* const* d_in, const int* in_sizes, int n_in,
                              void* d_out, int out_size, void* d_ws, size_t ws_size,
                              hipStream_t stream) {
    const void* x      = d_in[0];
    const void* w_attn = d_in[1];
    const void* b_attn = d_in[2];
    const void* w_proj = d_in[3];
    const void* b_proj = d_in[4];
    const void* rel    = d_in[5];
    char* ws = (char*)d_ws;
    int*            flag = (int*)(ws + 0);
    unsigned short* wTa  = (unsigned short*)(ws + 4096);
    unsigned short* wTp  = (unsigned short*)(ws + 3543040);
    unsigned short* x_bf = (unsigned short*)(ws + 4722688);
    unsigned short* relb = (unsigned short*)(ws + 17305600);
    unsigned short* bab  = (unsigned short*)(ws + 17567616);
    unsigned short* bpb  = (unsigned short*)(ws + 17572224);
    unsigned short* q_ws = (unsigned short*)(ws + 17573760);
    unsigned short* k_ws = (unsigned short*)(ws + 30156672);
    unsigned short* v_ws = (unsigned short*)(ws + 42739584);
    unsigned short* att  = x_bf;  // reuse: x_bf dead after gemm_qkv

    detect_dtype<<<1, 256, 0, stream>>>((const unsigned int*)w_attn, flag);
    cast_x<<<6144, 256, 0, stream>>>(x, x_bf, flag);
    cast_small<<<524, 256, 0, stream>>>(rel, b_attn, b_proj, relb, bab, bpb, flag);
    transpose_w<<<dim3(36, 12), 256, 0, stream>>>(w_attn, wTa, 768, 2304, flag);
    transpose_w<<<dim3(12, 12), 256, 0, stream>>>(w_proj, wTp, 768, 768, flag);
    gemm_qkv<<<dim3(64, 18), 256, 0, stream>>>(x_bf, wTa, bab, relb, q_ws, k_ws, v_ws);
    attn_fused<<<1536, 256, 0, stream>>>(q_ws, k_ws, v_ws, att);
    gemm_proj<<<dim3(64, 6), 256, 0, stream>>>(att, wTp, bpb, flag, (void*)d_out);
}

// Round 5
// 279.575 us; speedup vs baseline: 1.0083x; 1.0083x over previous
//
#include <hip/hip_runtime.h>
#include <stdint.h>

// Pipeline: detect dtype -> cast inputs to bf16 -> transpose weights ->
//   GEMM1(x @ w_attn^T, scatter Q*scale / K+rel / V^T) -> flash attention ->
//   GEMM2 (+b_proj) -> out (dtype matches detected input dtype)
//
// Workspace layout (bytes):
//   flag (int)            @ 0
//   wTa  [2304][768] bf16 @ 4096        (3538944)
//   wTp  [768][768]  bf16 @ 3543040     (1179648)
//   x_bf [8192][768] bf16 @ 4722688     (12582912)  -- later reused as att
//   rel_bf [2047][64]     @ 17305600    (262016)
//   ba_bf [2304]          @ 17567616    (4608)
//   bp_bf [768]           @ 17572224    (1536)
//   Q_ws [b][h][t][64]    @ 17573760    (12582912)  (scale folded)
//   K_ws [b][h][t][64]    @ 30156672    (12582912)  (rel folded)
//   V_ws [b][h][64][t]    @ 42739584    (12582912)  (transposed)
//   att  [b*t][768]       @ 4722688     (aliases x_bf; safe: stream-ordered)

typedef __attribute__((ext_vector_type(8))) short short8;
typedef __attribute__((ext_vector_type(4))) float f32x4;
typedef __attribute__((ext_vector_type(4))) unsigned short ushort4v;

#define DEV static __device__ __forceinline__

DEV float bf2f(unsigned short u) {
    union { unsigned int u; float f; } v; v.u = ((unsigned int)u) << 16; return v.f;
}
DEV unsigned short f2bf(float f) {
    union { float f; unsigned int u; } v; v.f = f;
    unsigned int u = v.u;
    return (unsigned short)((u + 0x7fffu + ((u >> 16) & 1u)) >> 16);
}

typedef const __attribute__((address_space(1))) void* gas_ptr;
typedef __attribute__((address_space(3))) void* las_ptr;
DEV void glds16(const void* g, void* l) {
    __builtin_amdgcn_global_load_lds((gas_ptr)g, (las_ptr)l, 16, 0, 0);
}

// ---------------- dtype detector ----------------
__global__ void detect_dtype(const unsigned int* __restrict__ w, int* __restrict__ flag) {
    __shared__ int cnt;
    if (threadIdx.x == 0) cnt = 0;
    __syncthreads();
    int c = 0;
    for (int i = threadIdx.x; i < 8192; i += 256) {
        unsigned int b1 = (w[i] >> 8) & 0x7F;
        c += (b1 >= 0x38 && b1 <= 0x3E) ? 1 : 0;
    }
    atomicAdd(&cnt, c);
    __syncthreads();
    if (threadIdx.x == 0) *flag = (cnt > 4096) ? 1 : 0;  // 1 = bf16 inputs
}

// ---------------- casts ----------------
__global__ __launch_bounds__(256) void cast_x(
    const void* __restrict__ x, unsigned short* __restrict__ xo,
    const int* __restrict__ flag)
{
    int i = (blockIdx.x * 256 + threadIdx.x) * 4;
    if (*flag) {
        *(ushort4v*)(xo + i) = *(const ushort4v*)((const unsigned short*)x + i);
    } else {
        f32x4 v = *(const f32x4*)((const float*)x + i);
        ushort4v o;
#pragma unroll
        for (int j = 0; j < 4; ++j) o[j] = f2bf(v[j]);
        *(ushort4v*)(xo + i) = o;
    }
}

__global__ __launch_bounds__(256) void cast_small(
    const void* __restrict__ rel, const void* __restrict__ ba, const void* __restrict__ bp,
    unsigned short* __restrict__ rel_o, unsigned short* __restrict__ ba_o,
    unsigned short* __restrict__ bp_o, const int* __restrict__ flag)
{
    int i = blockIdx.x * 256 + threadIdx.x;
    if (i >= 134080) return;
    int isbf = *flag;
    const void* src; unsigned short* dst; int off;
    if (i < 131008)      { src = rel; dst = rel_o; off = i; }
    else if (i < 133312) { src = ba;  dst = ba_o;  off = i - 131008; }
    else                 { src = bp;  dst = bp_o;  off = i - 133312; }
    dst[off] = isbf ? ((const unsigned short*)src)[off]
                    : f2bf(((const float*)src)[off]);
}

// ---------------- weight transpose (either dtype in, bf16 out), 64x64 tiles ----
__global__ __launch_bounds__(256) void transpose_w(
    const void* __restrict__ in, unsigned short* __restrict__ out,
    int R, int C, const int* __restrict__ flag)
{
    __shared__ unsigned short tile[64][66];
    const int t = threadIdx.x;
    const int cb = blockIdx.x * 64;
    const int rb = blockIdx.y * 64;
    if (*flag) {
        const unsigned short* inp = (const unsigned short*)in;
        const int c8 = (t & 7) * 8;
        const int r = t >> 3;
#pragma unroll
        for (int p = 0; p < 2; ++p) {
            int rr = r + p * 32;
            short8 v = *(const short8*)(inp + (size_t)(rb + rr) * C + cb + c8);
#pragma unroll
            for (int i = 0; i < 8; ++i) tile[rr][c8 + i] = (unsigned short)v[i];
        }
    } else {
        const float* inp = (const float*)in;
        const int c4 = (t & 15) * 4;
        const int r = t >> 4;
#pragma unroll
        for (int p = 0; p < 4; ++p) {
            int rr = r + p * 16;
            f32x4 v = *(const f32x4*)(inp + (size_t)(rb + rr) * C + cb + c4);
#pragma unroll
            for (int i = 0; i < 4; ++i) tile[rr][c4 + i] = f2bf(v[i]);
        }
    }
    __syncthreads();
    {
        const int c8 = (t & 7) * 8;
        const int r = t >> 3;
#pragma unroll
        for (int p = 0; p < 2; ++p) {
            int oc = r + p * 32;
            short8 v;
#pragma unroll
            for (int i = 0; i < 8; ++i) v[i] = (short)tile[c8 + i][oc];
            *(short8*)(out + (size_t)(cb + oc) * R + rb + c8) = v;
        }
    }
}

// ---------------- GEMM skeleton: 128x128 tile, BK=32, 4 waves ----------------
#define GEMM_PROLOG(A_, Bt_)                                                     \
    __shared__ __align__(16) unsigned short Abuf[128 * 32];                      \
    __shared__ __align__(16) unsigned short Bbuf[128 * 32];                      \
    const int t = threadIdx.x;                                                   \
    const int wave = t >> 6, lane = t & 63;                                      \
    const int lo = lane & 15, hi = lane >> 4;                                    \
    const int wr = wave >> 1, wc = wave & 1;                                     \
    const int bm = blockIdx.x * 128;                                             \
    const int bn = blockIdx.y * 128;                                             \
    int L0 = t << 4, L1 = (t + 256) << 4;                                        \
    int S0 = L0 ^ (((L0 >> 7) & 3) << 4);                                        \
    int S1 = L1 ^ (((L1 >> 7) & 3) << 4);                                        \
    int r0 = S0 >> 6, o0 = (S0 & 63) >> 1;                                       \
    int r1 = S1 >> 6, o1 = (S1 & 63) >> 1;                                       \
    const unsigned short* Ab = (A_) + (size_t)bm * 768;                          \
    const unsigned short* Bb = (Bt_) + (size_t)bn * 768;                         \
    char* lA0 = (char*)Abuf + ((wave * 64) << 4);                                \
    char* lA1 = (char*)Abuf + ((256 + wave * 64) << 4);                          \
    char* lB0 = (char*)Bbuf + ((wave * 64) << 4);                                \
    char* lB1 = (char*)Bbuf + ((256 + wave * 64) << 4);                          \
    const char* ap[4]; const char* bp_[4];                                       \
    _Pragma("unroll")                                                            \
    for (int m = 0; m < 4; ++m) {                                                \
        int Pa = ((wr * 64 + m * 16 + lo) << 6) + (hi << 4);                     \
        ap[m] = (const char*)Abuf + (Pa ^ (((Pa >> 7) & 3) << 4));               \
        int Pb = ((wc * 64 + m * 16 + lo) << 6) + (hi << 4);                     \
        bp_[m] = (const char*)Bbuf + (Pb ^ (((Pb >> 7) & 3) << 4));              \
    }                                                                            \
    f32x4 acc[4][4];                                                             \
    _Pragma("unroll")                                                            \
    for (int m = 0; m < 4; ++m)                                                  \
        _Pragma("unroll")                                                        \
        for (int n = 0; n < 4; ++n) acc[m][n] = (f32x4){0.f, 0.f, 0.f, 0.f};     \
    for (int k0 = 0; k0 < 768; k0 += 32) {                                       \
        glds16(Ab + (size_t)r0 * 768 + k0 + o0, lA0);                            \
        glds16(Ab + (size_t)r1 * 768 + k0 + o1, lA1);                            \
        glds16(Bb + (size_t)r0 * 768 + k0 + o0, lB0);                            \
        glds16(Bb + (size_t)r1 * 768 + k0 + o1, lB1);                            \
        __syncthreads();                                                         \
        short8 af[4], bfv[4];                                                    \
        _Pragma("unroll")                                                        \
        for (int m = 0; m < 4; ++m) af[m] = *(const short8*)ap[m];               \
        _Pragma("unroll")                                                        \
        for (int n = 0; n < 4; ++n) bfv[n] = *(const short8*)bp_[n];             \
        _Pragma("unroll")                                                        \
        for (int m = 0; m < 4; ++m)                                              \
            _Pragma("unroll")                                                    \
            for (int n = 0; n < 4; ++n)                                          \
                acc[m][n] = __builtin_amdgcn_mfma_f32_16x16x32_bf16(             \
                    af[m], bfv[n], acc[m][n], 0, 0, 0);                          \
        __syncthreads();                                                         \
    }

// GEMM1: epilogue scatters q (scaled), k (+rel), v (transposed)
__global__ __launch_bounds__(256) void gemm_qkv(
    const unsigned short* __restrict__ A,
    const unsigned short* __restrict__ Bt,
    const unsigned short* __restrict__ bias,
    const unsigned short* __restrict__ rel,
    unsigned short* __restrict__ q_ws,
    unsigned short* __restrict__ k_ws,
    unsigned short* __restrict__ v_ws)
{
    GEMM_PROLOG(A, Bt)
    const int gm0 = bm + wr * 64 + hi * 4;
#pragma unroll
    for (int m = 0; m < 4; ++m) {
        int gm = gm0 + m * 16;
        int b_ = gm >> 10;
        int tt = gm & 1023;
#pragma unroll
        for (int n = 0; n < 4; ++n) {
            int col = bn + wc * 64 + n * 16 + lo;
            float bs = bf2f(bias[col]);
            if (col < 768) {
                int h = col >> 6, d = col & 63;
                size_t base = (((size_t)b_ * 12 + h) * 1024 + tt) * 64 + d;
#pragma unroll
                for (int j = 0; j < 4; ++j)
                    q_ws[base + (size_t)j * 64] = f2bf((acc[m][n][j] + bs) * 0.125f);
            } else if (col < 1536) {
                int h = (col - 768) >> 6, d = col & 63;
                size_t base = (((size_t)b_ * 12 + h) * 1024 + tt) * 64 + d;
#pragma unroll
                for (int j = 0; j < 4; ++j) {
                    int trow = tt + j;
                    float rv = (trow > 0) ? bf2f(rel[(size_t)(trow - 1) * 64 + d]) : 0.f;
                    k_ws[base + (size_t)j * 64] = f2bf(acc[m][n][j] + bs + rv);
                }
            } else {
                int h = (col - 1536) >> 6, d = col & 63;
                size_t vb = (((size_t)b_ * 12 + h) * 64 + d) * 1024 + tt;
                ushort4v pk;
#pragma unroll
                for (int j = 0; j < 4; ++j) pk[j] = f2bf(acc[m][n][j] + bs);
                *(ushort4v*)(v_ws + vb) = pk;
            }
        }
    }
}

// GEMM2: att @ wT_proj + b_proj -> out (dtype per flag)
__global__ __launch_bounds__(256) void gemm_proj(
    const unsigned short* __restrict__ A,
    const unsigned short* __restrict__ Bt,
    const unsigned short* __restrict__ bias,
    const int* __restrict__ flag,
    void* __restrict__ outv)
{
    GEMM_PROLOG(A, Bt)
    const int isbf = *flag;
    const int gm0 = bm + wr * 64 + hi * 4;
#pragma unroll
    for (int m = 0; m < 4; ++m) {
        int gm = gm0 + m * 16;
#pragma unroll
        for (int n = 0; n < 4; ++n) {
            int col = bn + wc * 64 + n * 16 + lo;
            float bs = bf2f(bias[col]);
#pragma unroll
            for (int j = 0; j < 4; ++j) {
                float v = acc[m][n][j] + bs;
                if (isbf)
                    ((unsigned short*)outv)[(size_t)(gm + j) * 768 + col] = f2bf(v);
                else
                    ((float*)outv)[(size_t)(gm + j) * 768 + col] = v;
            }
        }
    }
}

// ---------------- flash attention (v4: KVBLK=128, uniform-work pairing) -------
// Wave-independent (no barriers), K/V direct from global (L2-resident).
// Each block: head bh, q-tile pair {15-p, p} -> uniform 9 passes of KVBLK=128.
// Per pass/wave: 16 QK^T MFMAs + softmax (amortized) + 16 PV MFMAs.
// P round-trip in wave-private LDS (16 rows x 256B, swizzle ^((row&7)<<4)).
// Grid 768 = 8 XCD x 12 heads x 8 pairs; gid&7 -> XCD owns its 12 heads' K/V.
__global__ __launch_bounds__(256, 3) void attn_fused(
    const unsigned short* __restrict__ q_ws,
    const unsigned short* __restrict__ k_ws,
    const unsigned short* __restrict__ v_ws,
    unsigned short* __restrict__ att)
{
    __shared__ __align__(16) unsigned short Pbuf[4][16 * 128];
    const int t = threadIdx.x;
    const int wave = t >> 6, lane = t & 63;
    const int lo = lane & 15, hi = lane >> 4;
    const int gid = blockIdx.x;
    const int xcd = gid & 7;
    const int c = gid >> 3;            // 0..95
    const int bh = xcd * 12 + (c % 12);
    const int pairIdx = c / 12;        // 0..7
    const int b_ = bh / 12, h = bh % 12;
    const size_t base = (size_t)bh * (1024 * 64);
    const unsigned short* Kb = k_ws + base;
    const unsigned short* Vb = v_ws + base;
    char* pb = (char*)&Pbuf[wave][0];

#pragma unroll 1
    for (int sel = 0; sel < 2; ++sel) {
        const int qt = sel ? pairIdx : (15 - pairIdx);
        const int q0w = qt * 64 + wave * 16;

        short8 qf[2];
#pragma unroll
        for (int kc = 0; kc < 2; ++kc)
            qf[kc] = *(const short8*)(q_ws + base +
                (size_t)(q0w + lo) * 64 + kc * 32 + hi * 8);

        f32x4 o[4];
        float mrun[4], lrun[4];
#pragma unroll
        for (int nt = 0; nt < 4; ++nt) o[nt] = (f32x4){0.f, 0.f, 0.f, 0.f};
#pragma unroll
        for (int j = 0; j < 4; ++j) { mrun[j] = -1e30f; lrun[j] = 0.f; }

        const int npass = (qt + 2) >> 1;
        for (int p = 0; p < npass; ++p) {
            const int kv0 = p * 128;
            // ---- QK^T over 128 KV columns ----
            f32x4 sc[8];
            __builtin_amdgcn_s_setprio(1);
#pragma unroll
            for (int nt = 0; nt < 8; ++nt) {
                const unsigned short* kr = Kb + (size_t)(kv0 + nt * 16 + lo) * 64 + hi * 8;
                short8 kf0 = *(const short8*)(kr);
                short8 kf1 = *(const short8*)(kr + 32);
                f32x4 z = (f32x4){0.f, 0.f, 0.f, 0.f};
                z = __builtin_amdgcn_mfma_f32_16x16x32_bf16(qf[0], kf0, z, 0, 0, 0);
                z = __builtin_amdgcn_mfma_f32_16x16x32_bf16(qf[1], kf1, z, 0, 0, 0);
                sc[nt] = z;
            }
            __builtin_amdgcn_s_setprio(0);
            // ---- causal mask (only diagonal-crossing passes) ----
            if (kv0 + 127 > q0w) {
#pragma unroll
                for (int nt = 0; nt < 8; ++nt)
#pragma unroll
                    for (int j = 0; j < 4; ++j) {
                        int qr = q0w + hi * 4 + j;
                        int kc_ = kv0 + nt * 16 + lo;
                        if (kc_ > qr) sc[nt][j] = -1e30f;
                    }
            }
            // ---- online softmax (defer-max, threshold 8) ----
            float mx[4];
            int need = 0;
#pragma unroll
            for (int j = 0; j < 4; ++j) {
                float m0 = sc[0][j];
#pragma unroll
                for (int nt = 1; nt < 8; ++nt) m0 = fmaxf(m0, sc[nt][j]);
                m0 = fmaxf(m0, __shfl_xor(m0, 1));
                m0 = fmaxf(m0, __shfl_xor(m0, 2));
                m0 = fmaxf(m0, __shfl_xor(m0, 4));
                m0 = fmaxf(m0, __shfl_xor(m0, 8));
                mx[j] = m0;
                need |= (m0 > mrun[j] + 8.f) ? 1 : 0;
            }
            if (__any(need)) {
#pragma unroll
                for (int j = 0; j < 4; ++j) {
                    float nm = fmaxf(mrun[j], mx[j]);
                    float corr = __expf(mrun[j] - nm);
                    mrun[j] = nm;
                    lrun[j] *= corr;
#pragma unroll
                    for (int nt = 0; nt < 4; ++nt) o[nt][j] *= corr;
                }
            }
#pragma unroll
            for (int j = 0; j < 4; ++j) {
                float rs = 0.f;
#pragma unroll
                for (int nt = 0; nt < 8; ++nt) {
                    float pv = __expf(sc[nt][j] - mrun[j]);
                    sc[nt][j] = pv;
                    rs += pv;
                }
                rs += __shfl_xor(rs, 1);
                rs += __shfl_xor(rs, 2);
                rs += __shfl_xor(rs, 4);
                rs += __shfl_xor(rs, 8);
                lrun[j] += rs;
            }
            // ---- P -> LDS (wave-private; rows 256B, swizzle bits6:4 ^= row&7) ----
#pragma unroll
            for (int nt = 0; nt < 8; ++nt)
#pragma unroll
                for (int j = 0; j < 4; ++j) {
                    int row = hi * 4 + j;
                    int addr = (row << 8) + (((nt * 32) + (lo << 1)) ^ ((row & 7) << 4));
                    *(unsigned short*)(pb + addr) = f2bf(sc[nt][j]);
                }
            // ---- PV over 4 k-chunks of 32 ----
#pragma unroll
            for (int c2 = 0; c2 < 4; ++c2) {
                int raddr = (lo << 8) + ((c2 * 64 + hi * 16) ^ ((lo & 7) << 4));
                short8 pf = *(const short8*)(pb + raddr);
                __builtin_amdgcn_s_setprio(1);
#pragma unroll
                for (int nt = 0; nt < 4; ++nt) {
                    short8 vf = *(const short8*)(Vb +
                        (size_t)(nt * 16 + lo) * 1024 + kv0 + c2 * 32 + hi * 8);
                    o[nt] = __builtin_amdgcn_mfma_f32_16x16x32_bf16(pf, vf, o[nt], 0, 0, 0);
                }
                __builtin_amdgcn_s_setprio(0);
            }
        }
        // ---- epilogue ----
#pragma unroll
        for (int j = 0; j < 4; ++j) {
            int tt = q0w + hi * 4 + j;
            float inv = 1.f / lrun[j];
#pragma unroll
            for (int nt = 0; nt < 4; ++nt)
                att[((size_t)(b_ * 1024 + tt)) * 768 + h * 64 + nt * 16 + lo] =
                    f2bf(o[nt][j] * inv);
        }
    }
}

extern "C" void kernel_launch(void* const* d_in, const int* in_sizes, int n_in,
                              void* d_out, int out_size, void* d_ws, size_t ws_size,
                              hipStream_t stream) {
    const void* x      = d_in[0];
    const void* w_attn = d_in[1];
    const void* b_attn = d_in[2];
    const void* w_proj = d_in[3];
    const void* b_proj = d_in[4];
    const void* rel    = d_in[5];
    char* ws = (char*)d_ws;
    int*            flag = (int*)(ws + 0);
    unsigned short* wTa  = (unsigned short*)(ws + 4096);
    unsigned short* wTp  = (unsigned short*)(ws + 3543040);
    unsigned short* x_bf = (unsigned short*)(ws + 4722688);
    unsigned short* relb = (unsigned short*)(ws + 17305600);
    unsigned short* bab  = (unsigned short*)(ws + 17567616);
    unsigned short* bpb  = (unsigned short*)(ws + 17572224);
    unsigned short* q_ws = (unsigned short*)(ws + 17573760);
    unsigned short* k_ws = (unsigned short*)(ws + 30156672);
    unsigned short* v_ws = (unsigned short*)(ws + 42739584);
    unsigned short* att  = x_bf;  // reuse: x_bf dead after gemm_qkv

    detect_dtype<<<1, 256, 0, stream>>>((const unsigned int*)w_attn, flag);
    cast_x<<<6144, 256, 0, stream>>>(x, x_bf, flag);
    cast_small<<<524, 256, 0, stream>>>(rel, b_attn, b_proj, relb, bab, bpb, flag);
    transpose_w<<<dim3(36, 12), 256, 0, stream>>>(w_attn, wTa, 768, 2304, flag);
    transpose_w<<<dim3(12, 12), 256, 0, stream>>>(w_proj, wTp, 768, 768, flag);
    gemm_qkv<<<dim3(64, 18), 256, 0, stream>>>(x_bf, wTa, bab, relb, q_ws, k_ws, v_ws);
    attn_fused<<<768, 256, 0, stream>>>(q_ws, k_ws, v_ws, att);
    gemm_proj<<<dim3(64, 6), 256, 0, stream>>>(att, wTp, bpb, flag, (void*)d_out);
}

// Round 6
// 241.023 us; speedup vs baseline: 1.1696x; 1.1600x over previous
//
#include <hip/hip_runtime.h>
#include <stdint.h>

// Pipeline: detect dtype -> cast inputs to bf16 -> transpose weights ->
//   GEMM1(x @ w_attn^T, scatter Q*scale / K+rel / V^T) -> flash attention ->
//   GEMM2 (+b_proj) -> out (dtype matches detected input dtype)

typedef __attribute__((ext_vector_type(8))) short short8;
typedef __attribute__((ext_vector_type(4))) float f32x4;
typedef __attribute__((ext_vector_type(4))) unsigned short ushort4v;

#define DEV static __device__ __forceinline__

DEV float bf2f(unsigned short u) {
    union { unsigned int u; float f; } v; v.u = ((unsigned int)u) << 16; return v.f;
}
DEV unsigned short f2bf(float f) {
    union { float f; unsigned int u; } v; v.f = f;
    unsigned int u = v.u;
    return (unsigned short)((u + 0x7fffu + ((u >> 16) & 1u)) >> 16);
}

typedef const __attribute__((address_space(1))) void* gas_ptr;
typedef __attribute__((address_space(3))) void* las_ptr;
DEV void glds16(const void* g, void* l) {
    __builtin_amdgcn_global_load_lds((gas_ptr)g, (las_ptr)l, 16, 0, 0);
}

// ---------------- dtype detector ----------------
__global__ void detect_dtype(const unsigned int* __restrict__ w, int* __restrict__ flag) {
    __shared__ int cnt;
    if (threadIdx.x == 0) cnt = 0;
    __syncthreads();
    int c = 0;
    for (int i = threadIdx.x; i < 8192; i += 256) {
        unsigned int b1 = (w[i] >> 8) & 0x7F;
        c += (b1 >= 0x38 && b1 <= 0x3E) ? 1 : 0;
    }
    atomicAdd(&cnt, c);
    __syncthreads();
    if (threadIdx.x == 0) *flag = (cnt > 4096) ? 1 : 0;  // 1 = bf16 inputs
}

// ---------------- casts ----------------
__global__ __launch_bounds__(256) void cast_x(
    const void* __restrict__ x, unsigned short* __restrict__ xo,
    const int* __restrict__ flag)
{
    int i = (blockIdx.x * 256 + threadIdx.x) * 4;
    if (*flag) {
        *(ushort4v*)(xo + i) = *(const ushort4v*)((const unsigned short*)x + i);
    } else {
        f32x4 v = *(const f32x4*)((const float*)x + i);
        ushort4v o;
#pragma unroll
        for (int j = 0; j < 4; ++j) o[j] = f2bf(v[j]);
        *(ushort4v*)(xo + i) = o;
    }
}

__global__ __launch_bounds__(256) void cast_small(
    const void* __restrict__ rel, const void* __restrict__ ba, const void* __restrict__ bp,
    unsigned short* __restrict__ rel_o, unsigned short* __restrict__ ba_o,
    unsigned short* __restrict__ bp_o, const int* __restrict__ flag)
{
    int i = blockIdx.x * 256 + threadIdx.x;
    if (i >= 134080) return;
    int isbf = *flag;
    const void* src; unsigned short* dst; int off;
    if (i < 131008)      { src = rel; dst = rel_o; off = i; }
    else if (i < 133312) { src = ba;  dst = ba_o;  off = i - 131008; }
    else                 { src = bp;  dst = bp_o;  off = i - 133312; }
    dst[off] = isbf ? ((const unsigned short*)src)[off]
                    : f2bf(((const float*)src)[off]);
}

// ---------------- weight transpose (either dtype in, bf16 out), 64x64 tiles ----
__global__ __launch_bounds__(256) void transpose_w(
    const void* __restrict__ in, unsigned short* __restrict__ out,
    int R, int C, const int* __restrict__ flag)
{
    __shared__ unsigned short tile[64][66];
    const int t = threadIdx.x;
    const int cb = blockIdx.x * 64;
    const int rb = blockIdx.y * 64;
    if (*flag) {
        const unsigned short* inp = (const unsigned short*)in;
        const int c8 = (t & 7) * 8;
        const int r = t >> 3;
#pragma unroll
        for (int p = 0; p < 2; ++p) {
            int rr = r + p * 32;
            short8 v = *(const short8*)(inp + (size_t)(rb + rr) * C + cb + c8);
#pragma unroll
            for (int i = 0; i < 8; ++i) tile[rr][c8 + i] = (unsigned short)v[i];
        }
    } else {
        const float* inp = (const float*)in;
        const int c4 = (t & 15) * 4;
        const int r = t >> 4;
#pragma unroll
        for (int p = 0; p < 4; ++p) {
            int rr = r + p * 16;
            f32x4 v = *(const f32x4*)(inp + (size_t)(rb + rr) * C + cb + c4);
#pragma unroll
            for (int i = 0; i < 4; ++i) tile[rr][c4 + i] = f2bf(v[i]);
        }
    }
    __syncthreads();
    {
        const int c8 = (t & 7) * 8;
        const int r = t >> 3;
#pragma unroll
        for (int p = 0; p < 2; ++p) {
            int oc = r + p * 32;
            short8 v;
#pragma unroll
            for (int i = 0; i < 8; ++i) v[i] = (short)tile[c8 + i][oc];
            *(short8*)(out + (size_t)(cb + oc) * R + rb + c8) = v;
        }
    }
}

// ---------------- GEMM skeleton: 128x128 tile, BK=32, 4 waves ----------------
#define GEMM_PROLOG(A_, Bt_)                                                     \
    __shared__ __align__(16) unsigned short Abuf[128 * 32];                      \
    __shared__ __align__(16) unsigned short Bbuf[128 * 32];                      \
    const int t = threadIdx.x;                                                   \
    const int wave = t >> 6, lane = t & 63;                                      \
    const int lo = lane & 15, hi = lane >> 4;                                    \
    const int wr = wave >> 1, wc = wave & 1;                                     \
    const int bm = blockIdx.x * 128;                                             \
    const int bn = blockIdx.y * 128;                                             \
    int L0 = t << 4, L1 = (t + 256) << 4;                                        \
    int S0 = L0 ^ (((L0 >> 7) & 3) << 4);                                        \
    int S1 = L1 ^ (((L1 >> 7) & 3) << 4);                                        \
    int r0 = S0 >> 6, o0 = (S0 & 63) >> 1;                                       \
    int r1 = S1 >> 6, o1 = (S1 & 63) >> 1;                                       \
    const unsigned short* Ab = (A_) + (size_t)bm * 768;                          \
    const unsigned short* Bb = (Bt_) + (size_t)bn * 768;                         \
    char* lA0 = (char*)Abuf + ((wave * 64) << 4);                                \
    char* lA1 = (char*)Abuf + ((256 + wave * 64) << 4);                          \
    char* lB0 = (char*)Bbuf + ((wave * 64) << 4);                                \
    char* lB1 = (char*)Bbuf + ((256 + wave * 64) << 4);                          \
    const char* ap[4]; const char* bp_[4];                                       \
    _Pragma("unroll")                                                            \
    for (int m = 0; m < 4; ++m) {                                                \
        int Pa = ((wr * 64 + m * 16 + lo) << 6) + (hi << 4);                     \
        ap[m] = (const char*)Abuf + (Pa ^ (((Pa >> 7) & 3) << 4));               \
        int Pb = ((wc * 64 + m * 16 + lo) << 6) + (hi << 4);                     \
        bp_[m] = (const char*)Bbuf + (Pb ^ (((Pb >> 7) & 3) << 4));              \
    }                                                                            \
    f32x4 acc[4][4];                                                             \
    _Pragma("unroll")                                                            \
    for (int m = 0; m < 4; ++m)                                                  \
        _Pragma("unroll")                                                        \
        for (int n = 0; n < 4; ++n) acc[m][n] = (f32x4){0.f, 0.f, 0.f, 0.f};     \
    for (int k0 = 0; k0 < 768; k0 += 32) {                                       \
        glds16(Ab + (size_t)r0 * 768 + k0 + o0, lA0);                            \
        glds16(Ab + (size_t)r1 * 768 + k0 + o1, lA1);                            \
        glds16(Bb + (size_t)r0 * 768 + k0 + o0, lB0);                            \
        glds16(Bb + (size_t)r1 * 768 + k0 + o1, lB1);                            \
        __syncthreads();                                                         \
        short8 af[4], bfv[4];                                                    \
        _Pragma("unroll")                                                        \
        for (int m = 0; m < 4; ++m) af[m] = *(const short8*)ap[m];               \
        _Pragma("unroll")                                                        \
        for (int n = 0; n < 4; ++n) bfv[n] = *(const short8*)bp_[n];             \
        _Pragma("unroll")                                                        \
        for (int m = 0; m < 4; ++m)                                              \
            _Pragma("unroll")                                                    \
            for (int n = 0; n < 4; ++n)                                          \
                acc[m][n] = __builtin_amdgcn_mfma_f32_16x16x32_bf16(             \
                    af[m], bfv[n], acc[m][n], 0, 0, 0);                          \
        __syncthreads();                                                         \
    }

// GEMM1: epilogue scatters q (scaled), k (+rel), v (transposed)
__global__ __launch_bounds__(256) void gemm_qkv(
    const unsigned short* __restrict__ A,
    const unsigned short* __restrict__ Bt,
    const unsigned short* __restrict__ bias,
    const unsigned short* __restrict__ rel,
    unsigned short* __restrict__ q_ws,
    unsigned short* __restrict__ k_ws,
    unsigned short* __restrict__ v_ws)
{
    GEMM_PROLOG(A, Bt)
    const int gm0 = bm + wr * 64 + hi * 4;
#pragma unroll
    for (int m = 0; m < 4; ++m) {
        int gm = gm0 + m * 16;
        int b_ = gm >> 10;
        int tt = gm & 1023;
#pragma unroll
        for (int n = 0; n < 4; ++n) {
            int col = bn + wc * 64 + n * 16 + lo;
            float bs = bf2f(bias[col]);
            if (col < 768) {
                int h = col >> 6, d = col & 63;
                size_t base = (((size_t)b_ * 12 + h) * 1024 + tt) * 64 + d;
#pragma unroll
                for (int j = 0; j < 4; ++j)
                    q_ws[base + (size_t)j * 64] = f2bf((acc[m][n][j] + bs) * 0.125f);
            } else if (col < 1536) {
                int h = (col - 768) >> 6, d = col & 63;
                size_t base = (((size_t)b_ * 12 + h) * 1024 + tt) * 64 + d;
#pragma unroll
                for (int j = 0; j < 4; ++j) {
                    int trow = tt + j;
                    float rv = (trow > 0) ? bf2f(rel[(size_t)(trow - 1) * 64 + d]) : 0.f;
                    k_ws[base + (size_t)j * 64] = f2bf(acc[m][n][j] + bs + rv);
                }
            } else {
                int h = (col - 1536) >> 6, d = col & 63;
                size_t vb = (((size_t)b_ * 12 + h) * 64 + d) * 1024 + tt;
                ushort4v pk;
#pragma unroll
                for (int j = 0; j < 4; ++j) pk[j] = f2bf(acc[m][n][j] + bs);
                *(ushort4v*)(v_ws + vb) = pk;
            }
        }
    }
}

// GEMM2: att @ wT_proj + b_proj -> out (dtype per flag)
__global__ __launch_bounds__(256) void gemm_proj(
    const unsigned short* __restrict__ A,
    const unsigned short* __restrict__ Bt,
    const unsigned short* __restrict__ bias,
    const int* __restrict__ flag,
    void* __restrict__ outv)
{
    GEMM_PROLOG(A, Bt)
    const int isbf = *flag;
    const int gm0 = bm + wr * 64 + hi * 4;
#pragma unroll
    for (int m = 0; m < 4; ++m) {
        int gm = gm0 + m * 16;
#pragma unroll
        for (int n = 0; n < 4; ++n) {
            int col = bn + wc * 64 + n * 16 + lo;
            float bs = bf2f(bias[col]);
#pragma unroll
            for (int j = 0; j < 4; ++j) {
                float v = acc[m][n][j] + bs;
                if (isbf)
                    ((unsigned short*)outv)[(size_t)(gm + j) * 768 + col] = f2bf(v);
                else
                    ((float*)outv)[(size_t)(gm + j) * 768 + col] = v;
            }
        }
    }
}

// ---------------- flash attention (v5: LDS-staged + uniform pairing) ----------
// R3's verified staging/compute body (KVBLK=64, dbuf global_load_lds, XOR
// swizzle) + v4's uniform work pairing: block handles q-tiles {15-p, p} ->
// exactly 17 KV-tiles per block. Grid 768 = 8 XCD x 12 heads x 8 pairs ->
// flat 3 blocks/CU. Staging is per-BLOCK (4-way wave reuse) fixing the L2-BW
// bound measured in v3/v4. Defer-max softmax (threshold 8).
__global__ __launch_bounds__(256) void attn_fused(
    const unsigned short* __restrict__ q_ws,
    const unsigned short* __restrict__ k_ws,
    const unsigned short* __restrict__ v_ws,
    unsigned short* __restrict__ att)
{
    __shared__ __align__(16) unsigned short Kbuf[2][64 * 64];
    __shared__ __align__(16) unsigned short Vbuf[2][64 * 64];
    __shared__ __align__(16) unsigned short Pbuf[4][16 * 64];
    const int t = threadIdx.x;
    const int wave = t >> 6, lane = t & 63;
    const int lo = lane & 15, hi = lane >> 4;
    const int gid = blockIdx.x;
    const int xcd = gid & 7;
    const int c = gid >> 3;            // 0..95
    const int bh = xcd * 12 + (c % 12);
    const int pairIdx = c / 12;        // 0..7
    const int b_ = bh / 12, h = bh % 12;
    const size_t base = (size_t)bh * (1024 * 64);
    const unsigned short* Kb = k_ws + base;
    const unsigned short* Vb = v_ws + base;

    // staging offsets: linear LDS dest (t*16B), pre-swizzled global source
    int L0 = t << 4, L1 = (t + 256) << 4;
    int S0 = L0 ^ (((L0 >> 7) & 7) << 4);
    int S1 = L1 ^ (((L1 >> 7) & 7) << 4);
    int r0 = S0 >> 7, o0 = (S0 & 127) >> 1;
    int r1 = S1 >> 7, o1 = (S1 & 127) >> 1;
    const int lof0 = (wave * 64) << 4;
    const int lof1 = (256 + wave * 64) << 4;

    // swizzled K/V fragment read offsets (128B rows, ^((row&7)<<4))
    int koff[4][2];
#pragma unroll
    for (int nt = 0; nt < 4; ++nt)
#pragma unroll
        for (int kc = 0; kc < 2; ++kc) {
            int P = ((nt * 16 + lo) << 7) + (kc << 6) + (hi << 4);
            koff[nt][kc] = P ^ (((P >> 7) & 7) << 4);
        }
    int poffR[2];
#pragma unroll
    for (int kc = 0; kc < 2; ++kc) {
        int P = (lo << 7) + (kc << 6) + (hi << 4);
        poffR[kc] = P ^ (((P >> 7) & 7) << 4);
    }
    int poffW[4][4];
#pragma unroll
    for (int nt = 0; nt < 4; ++nt)
#pragma unroll
        for (int j = 0; j < 4; ++j) {
            int P = ((hi * 4 + j) << 7) + ((nt * 16 + lo) << 1);
            poffW[nt][j] = P ^ (((P >> 7) & 7) << 4);
        }
    char* pb = (char*)&Pbuf[wave][0];

#pragma unroll 1
    for (int sel = 0; sel < 2; ++sel) {
        const int qt = sel ? pairIdx : (15 - pairIdx);
        const int q0w = qt * 64 + wave * 16;

        short8 qf[2];
#pragma unroll
        for (int kc = 0; kc < 2; ++kc)
            qf[kc] = *(const short8*)(q_ws + base +
                (size_t)(q0w + lo) * 64 + kc * 32 + hi * 8);

        f32x4 o[4];
        float mrun[4], lrun[4];
#pragma unroll
        for (int nt = 0; nt < 4; ++nt) o[nt] = (f32x4){0.f, 0.f, 0.f, 0.f};
#pragma unroll
        for (int j = 0; j < 4; ++j) { mrun[j] = -1e30f; lrun[j] = 0.f; }

        // barrier between sels: prior tile reads must finish before restaging
        if (sel) __syncthreads();
        // prologue: stage tile 0 into buffer 0
        glds16(Kb + (size_t)r0 * 64 + o0, (char*)Kbuf[0] + lof0);
        glds16(Kb + (size_t)r1 * 64 + o1, (char*)Kbuf[0] + lof1);
        glds16(Vb + (size_t)r0 * 1024 + o0, (char*)Vbuf[0] + lof0);
        glds16(Vb + (size_t)r1 * 1024 + o1, (char*)Vbuf[0] + lof1);

        int cur = 0;
        const int nkt = qt + 1;
        for (int kt = 0; kt < nkt; ++kt) {
            __syncthreads();  // staging of tile kt complete (vmcnt drained)
            if (kt + 1 < nkt) {
                const int kn = (kt + 1) * 64;
                glds16(Kb + (size_t)(kn + r0) * 64 + o0, (char*)Kbuf[cur ^ 1] + lof0);
                glds16(Kb + (size_t)(kn + r1) * 64 + o1, (char*)Kbuf[cur ^ 1] + lof1);
                glds16(Vb + (size_t)r0 * 1024 + kn + o0, (char*)Vbuf[cur ^ 1] + lof0);
                glds16(Vb + (size_t)r1 * 1024 + kn + o1, (char*)Vbuf[cur ^ 1] + lof1);
            }
            const int kv0 = kt * 64;
            const char* Kc = (const char*)Kbuf[cur];
            const char* Vc = (const char*)Vbuf[cur];

            short8 kf[4][2];
#pragma unroll
            for (int nt = 0; nt < 4; ++nt)
#pragma unroll
                for (int kc = 0; kc < 2; ++kc)
                    kf[nt][kc] = *(const short8*)(Kc + koff[nt][kc]);
            f32x4 sc[4];
            __builtin_amdgcn_s_setprio(1);
#pragma unroll
            for (int nt = 0; nt < 4; ++nt) {
                f32x4 z = (f32x4){0.f, 0.f, 0.f, 0.f};
                z = __builtin_amdgcn_mfma_f32_16x16x32_bf16(qf[0], kf[nt][0], z, 0, 0, 0);
                z = __builtin_amdgcn_mfma_f32_16x16x32_bf16(qf[1], kf[nt][1], z, 0, 0, 0);
                sc[nt] = z;
            }
            __builtin_amdgcn_s_setprio(0);
            if (kv0 + 63 > q0w) {
#pragma unroll
                for (int nt = 0; nt < 4; ++nt)
#pragma unroll
                    for (int j = 0; j < 4; ++j) {
                        int qr = q0w + hi * 4 + j;
                        int kc_ = kv0 + nt * 16 + lo;
                        if (kc_ > qr) sc[nt][j] = -1e30f;
                    }
            }
            // online softmax with defer-max (skip rescale when growth <= 8)
            float mx[4];
            int need = 0;
#pragma unroll
            for (int j = 0; j < 4; ++j) {
                float m0 = fmaxf(fmaxf(sc[0][j], sc[1][j]), fmaxf(sc[2][j], sc[3][j]));
                m0 = fmaxf(m0, __shfl_xor(m0, 1));
                m0 = fmaxf(m0, __shfl_xor(m0, 2));
                m0 = fmaxf(m0, __shfl_xor(m0, 4));
                m0 = fmaxf(m0, __shfl_xor(m0, 8));
                mx[j] = m0;
                need |= (m0 > mrun[j] + 8.f) ? 1 : 0;
            }
            if (__any(need)) {
#pragma unroll
                for (int j = 0; j < 4; ++j) {
                    float nm = fmaxf(mrun[j], mx[j]);
                    float corr = __expf(mrun[j] - nm);
                    mrun[j] = nm;
                    lrun[j] *= corr;
#pragma unroll
                    for (int nt = 0; nt < 4; ++nt) o[nt][j] *= corr;
                }
            }
#pragma unroll
            for (int j = 0; j < 4; ++j) {
                float rs = 0.f;
#pragma unroll
                for (int nt = 0; nt < 4; ++nt) {
                    float p = __expf(sc[nt][j] - mrun[j]);
                    sc[nt][j] = p;
                    rs += p;
                }
                rs += __shfl_xor(rs, 1);
                rs += __shfl_xor(rs, 2);
                rs += __shfl_xor(rs, 4);
                rs += __shfl_xor(rs, 8);
                lrun[j] += rs;
            }
            // V fragments (hoisted; LDS latency hides under P round-trip)
            short8 vf[4][2];
#pragma unroll
            for (int nt = 0; nt < 4; ++nt)
#pragma unroll
                for (int kc2 = 0; kc2 < 2; ++kc2)
                    vf[nt][kc2] = *(const short8*)(Vc + koff[nt][kc2]);
            // P -> LDS (wave-private, no barrier)
#pragma unroll
            for (int nt = 0; nt < 4; ++nt)
#pragma unroll
                for (int j = 0; j < 4; ++j)
                    *(unsigned short*)(pb + poffW[nt][j]) = f2bf(sc[nt][j]);
            // PV
#pragma unroll
            for (int kc2 = 0; kc2 < 2; ++kc2) {
                short8 pf = *(const short8*)(pb + poffR[kc2]);
                __builtin_amdgcn_s_setprio(1);
#pragma unroll
                for (int nt = 0; nt < 4; ++nt)
                    o[nt] = __builtin_amdgcn_mfma_f32_16x16x32_bf16(pf, vf[nt][kc2], o[nt], 0, 0, 0);
                __builtin_amdgcn_s_setprio(0);
            }
            cur ^= 1;
        }
        // epilogue
#pragma unroll
        for (int j = 0; j < 4; ++j) {
            int tt = q0w + hi * 4 + j;
            float inv = 1.f / lrun[j];
#pragma unroll
            for (int nt = 0; nt < 4; ++nt)
                att[((size_t)(b_ * 1024 + tt)) * 768 + h * 64 + nt * 16 + lo] =
                    f2bf(o[nt][j] * inv);
        }
    }
}

extern "C" void kernel_launch(void* const* d_in, const int* in_sizes, int n_in,
                              void* d_out, int out_size, void* d_ws, size_t ws_size,
                              hipStream_t stream) {
    const void* x      = d_in[0];
    const void* w_attn = d_in[1];
    const void* b_attn = d_in[2];
    const void* w_proj = d_in[3];
    const void* b_proj = d_in[4];
    const void* rel    = d_in[5];
    char* ws = (char*)d_ws;
    int*            flag = (int*)(ws + 0);
    unsigned short* wTa  = (unsigned short*)(ws + 4096);
    unsigned short* wTp  = (unsigned short*)(ws + 3543040);
    unsigned short* x_bf = (unsigned short*)(ws + 4722688);
    unsigned short* relb = (unsigned short*)(ws + 17305600);
    unsigned short* bab  = (unsigned short*)(ws + 17567616);
    unsigned short* bpb  = (unsigned short*)(ws + 17572224);
    unsigned short* q_ws = (unsigned short*)(ws + 17573760);
    unsigned short* k_ws = (unsigned short*)(ws + 30156672);
    unsigned short* v_ws = (unsigned short*)(ws + 42739584);
    unsigned short* att  = x_bf;  // reuse: x_bf dead after gemm_qkv

    detect_dtype<<<1, 256, 0, stream>>>((const unsigned int*)w_attn, flag);
    cast_x<<<6144, 256, 0, stream>>>(x, x_bf, flag);
    cast_small<<<524, 256, 0, stream>>>(rel, b_attn, b_proj, relb, bab, bpb, flag);
    transpose_w<<<dim3(36, 12), 256, 0, stream>>>(w_attn, wTa, 768, 2304, flag);
    transpose_w<<<dim3(12, 12), 256, 0, stream>>>(w_proj, wTp, 768, 768, flag);
    gemm_qkv<<<dim3(64, 18), 256, 0, stream>>>(x_bf, wTa, bab, relb, q_ws, k_ws, v_ws);
    attn_fused<<<768, 256, 0, stream>>>(q_ws, k_ws, v_ws, att);
    gemm_proj<<<dim3(64, 6), 256, 0, stream>>>(att, wTp, bpb, flag, (void*)d_out);
}

// Round 7
// 215.007 us; speedup vs baseline: 1.3111x; 1.1210x over previous
//
#include <hip/hip_runtime.h>
#include <stdint.h>

// Pipeline: detect dtype -> cast inputs to bf16 -> transpose weights ->
//   GEMM1(x @ w_attn^T, scatter Q*scale*log2e / K+rel / V^T) -> flash attention
//   (swapped-QK^T lane-local softmax, log2-domain) -> GEMM2 (+b_proj) -> out

typedef __attribute__((ext_vector_type(8))) short short8;
typedef __attribute__((ext_vector_type(4))) float f32x4;
typedef __attribute__((ext_vector_type(4))) unsigned short ushort4v;

#define DEV static __device__ __forceinline__

DEV float bf2f(unsigned short u) {
    union { unsigned int u; float f; } v; v.u = ((unsigned int)u) << 16; return v.f;
}
DEV unsigned short f2bf(float f) {
    union { float f; unsigned int u; } v; v.f = f;
    unsigned int u = v.u;
    return (unsigned short)((u + 0x7fffu + ((u >> 16) & 1u)) >> 16);
}

typedef const __attribute__((address_space(1))) void* gas_ptr;
typedef __attribute__((address_space(3))) void* las_ptr;
DEV void glds16(const void* g, void* l) {
    __builtin_amdgcn_global_load_lds((gas_ptr)g, (las_ptr)l, 16, 0, 0);
}

// ---------------- dtype detector ----------------
__global__ void detect_dtype(const unsigned int* __restrict__ w, int* __restrict__ flag) {
    __shared__ int cnt;
    if (threadIdx.x == 0) cnt = 0;
    __syncthreads();
    int c = 0;
    for (int i = threadIdx.x; i < 8192; i += 256) {
        unsigned int b1 = (w[i] >> 8) & 0x7F;
        c += (b1 >= 0x38 && b1 <= 0x3E) ? 1 : 0;
    }
    atomicAdd(&cnt, c);
    __syncthreads();
    if (threadIdx.x == 0) *flag = (cnt > 4096) ? 1 : 0;  // 1 = bf16 inputs
}

// ---------------- casts ----------------
__global__ __launch_bounds__(256) void cast_x(
    const void* __restrict__ x, unsigned short* __restrict__ xo,
    const int* __restrict__ flag)
{
    int i = (blockIdx.x * 256 + threadIdx.x) * 4;
    if (*flag) {
        *(ushort4v*)(xo + i) = *(const ushort4v*)((const unsigned short*)x + i);
    } else {
        f32x4 v = *(const f32x4*)((const float*)x + i);
        ushort4v o;
#pragma unroll
        for (int j = 0; j < 4; ++j) o[j] = f2bf(v[j]);
        *(ushort4v*)(xo + i) = o;
    }
}

__global__ __launch_bounds__(256) void cast_small(
    const void* __restrict__ rel, const void* __restrict__ ba, const void* __restrict__ bp,
    unsigned short* __restrict__ rel_o, unsigned short* __restrict__ ba_o,
    unsigned short* __restrict__ bp_o, const int* __restrict__ flag)
{
    int i = blockIdx.x * 256 + threadIdx.x;
    if (i >= 134080) return;
    int isbf = *flag;
    const void* src; unsigned short* dst; int off;
    if (i < 131008)      { src = rel; dst = rel_o; off = i; }
    else if (i < 133312) { src = ba;  dst = ba_o;  off = i - 131008; }
    else                 { src = bp;  dst = bp_o;  off = i - 133312; }
    dst[off] = isbf ? ((const unsigned short*)src)[off]
                    : f2bf(((const float*)src)[off]);
}

// ---------------- weight transpose (either dtype in, bf16 out), 64x64 tiles ----
__global__ __launch_bounds__(256) void transpose_w(
    const void* __restrict__ in, unsigned short* __restrict__ out,
    int R, int C, const int* __restrict__ flag)
{
    __shared__ unsigned short tile[64][66];
    const int t = threadIdx.x;
    const int cb = blockIdx.x * 64;
    const int rb = blockIdx.y * 64;
    if (*flag) {
        const unsigned short* inp = (const unsigned short*)in;
        const int c8 = (t & 7) * 8;
        const int r = t >> 3;
#pragma unroll
        for (int p = 0; p < 2; ++p) {
            int rr = r + p * 32;
            short8 v = *(const short8*)(inp + (size_t)(rb + rr) * C + cb + c8);
#pragma unroll
            for (int i = 0; i < 8; ++i) tile[rr][c8 + i] = (unsigned short)v[i];
        }
    } else {
        const float* inp = (const float*)in;
        const int c4 = (t & 15) * 4;
        const int r = t >> 4;
#pragma unroll
        for (int p = 0; p < 4; ++p) {
            int rr = r + p * 16;
            f32x4 v = *(const f32x4*)(inp + (size_t)(rb + rr) * C + cb + c4);
#pragma unroll
            for (int i = 0; i < 4; ++i) tile[rr][c4 + i] = f2bf(v[i]);
        }
    }
    __syncthreads();
    {
        const int c8 = (t & 7) * 8;
        const int r = t >> 3;
#pragma unroll
        for (int p = 0; p < 2; ++p) {
            int oc = r + p * 32;
            short8 v;
#pragma unroll
            for (int i = 0; i < 8; ++i) v[i] = (short)tile[c8 + i][oc];
            *(short8*)(out + (size_t)(cb + oc) * R + rb + c8) = v;
        }
    }
}

// ---------------- GEMM skeleton: 128x128 tile, BK=32, 4 waves ----------------
#define GEMM_PROLOG(A_, Bt_)                                                     \
    __shared__ __align__(16) unsigned short Abuf[128 * 32];                      \
    __shared__ __align__(16) unsigned short Bbuf[128 * 32];                      \
    const int t = threadIdx.x;                                                   \
    const int wave = t >> 6, lane = t & 63;                                      \
    const int lo = lane & 15, hi = lane >> 4;                                    \
    const int wr = wave >> 1, wc = wave & 1;                                     \
    const int bm = blockIdx.x * 128;                                             \
    const int bn = blockIdx.y * 128;                                             \
    int L0 = t << 4, L1 = (t + 256) << 4;                                        \
    int S0 = L0 ^ (((L0 >> 7) & 3) << 4);                                        \
    int S1 = L1 ^ (((L1 >> 7) & 3) << 4);                                        \
    int r0 = S0 >> 6, o0 = (S0 & 63) >> 1;                                       \
    int r1 = S1 >> 6, o1 = (S1 & 63) >> 1;                                       \
    const unsigned short* Ab = (A_) + (size_t)bm * 768;                          \
    const unsigned short* Bb = (Bt_) + (size_t)bn * 768;                         \
    char* lA0 = (char*)Abuf + ((wave * 64) << 4);                                \
    char* lA1 = (char*)Abuf + ((256 + wave * 64) << 4);                          \
    char* lB0 = (char*)Bbuf + ((wave * 64) << 4);                                \
    char* lB1 = (char*)Bbuf + ((256 + wave * 64) << 4);                          \
    const char* ap[4]; const char* bp_[4];                                       \
    _Pragma("unroll")                                                            \
    for (int m = 0; m < 4; ++m) {                                                \
        int Pa = ((wr * 64 + m * 16 + lo) << 6) + (hi << 4);                     \
        ap[m] = (const char*)Abuf + (Pa ^ (((Pa >> 7) & 3) << 4));               \
        int Pb = ((wc * 64 + m * 16 + lo) << 6) + (hi << 4);                     \
        bp_[m] = (const char*)Bbuf + (Pb ^ (((Pb >> 7) & 3) << 4));              \
    }                                                                            \
    f32x4 acc[4][4];                                                             \
    _Pragma("unroll")                                                            \
    for (int m = 0; m < 4; ++m)                                                  \
        _Pragma("unroll")                                                        \
        for (int n = 0; n < 4; ++n) acc[m][n] = (f32x4){0.f, 0.f, 0.f, 0.f};     \
    for (int k0 = 0; k0 < 768; k0 += 32) {                                       \
        glds16(Ab + (size_t)r0 * 768 + k0 + o0, lA0);                            \
        glds16(Ab + (size_t)r1 * 768 + k0 + o1, lA1);                            \
        glds16(Bb + (size_t)r0 * 768 + k0 + o0, lB0);                            \
        glds16(Bb + (size_t)r1 * 768 + k0 + o1, lB1);                            \
        __syncthreads();                                                         \
        short8 af[4], bfv[4];                                                    \
        _Pragma("unroll")                                                        \
        for (int m = 0; m < 4; ++m) af[m] = *(const short8*)ap[m];               \
        _Pragma("unroll")                                                        \
        for (int n = 0; n < 4; ++n) bfv[n] = *(const short8*)bp_[n];             \
        _Pragma("unroll")                                                        \
        for (int m = 0; m < 4; ++m)                                              \
            _Pragma("unroll")                                                    \
            for (int n = 0; n < 4; ++n)                                          \
                acc[m][n] = __builtin_amdgcn_mfma_f32_16x16x32_bf16(             \
                    af[m], bfv[n], acc[m][n], 0, 0, 0);                          \
        __syncthreads();                                                         \
    }

// GEMM1: epilogue scatters q (scale*log2e folded), k (+rel), v (transposed)
__global__ __launch_bounds__(256) void gemm_qkv(
    const unsigned short* __restrict__ A,
    const unsigned short* __restrict__ Bt,
    const unsigned short* __restrict__ bias,
    const unsigned short* __restrict__ rel,
    unsigned short* __restrict__ q_ws,
    unsigned short* __restrict__ k_ws,
    unsigned short* __restrict__ v_ws)
{
    GEMM_PROLOG(A, Bt)
    const int gm0 = bm + wr * 64 + hi * 4;
    const float QSCALE = 0.125f * 1.44269504f;  // fold log2e: scores in log2 units
#pragma unroll
    for (int m = 0; m < 4; ++m) {
        int gm = gm0 + m * 16;
        int b_ = gm >> 10;
        int tt = gm & 1023;
#pragma unroll
        for (int n = 0; n < 4; ++n) {
            int col = bn + wc * 64 + n * 16 + lo;
            float bs = bf2f(bias[col]);
            if (col < 768) {
                int h = col >> 6, d = col & 63;
                size_t base = (((size_t)b_ * 12 + h) * 1024 + tt) * 64 + d;
#pragma unroll
                for (int j = 0; j < 4; ++j)
                    q_ws[base + (size_t)j * 64] = f2bf((acc[m][n][j] + bs) * QSCALE);
            } else if (col < 1536) {
                int h = (col - 768) >> 6, d = col & 63;
                size_t base = (((size_t)b_ * 12 + h) * 1024 + tt) * 64 + d;
#pragma unroll
                for (int j = 0; j < 4; ++j) {
                    int trow = tt + j;
                    float rv = (trow > 0) ? bf2f(rel[(size_t)(trow - 1) * 64 + d]) : 0.f;
                    k_ws[base + (size_t)j * 64] = f2bf(acc[m][n][j] + bs + rv);
                }
            } else {
                int h = (col - 1536) >> 6, d = col & 63;
                size_t vb = (((size_t)b_ * 12 + h) * 64 + d) * 1024 + tt;
                ushort4v pk;
#pragma unroll
                for (int j = 0; j < 4; ++j) pk[j] = f2bf(acc[m][n][j] + bs);
                *(ushort4v*)(v_ws + vb) = pk;
            }
        }
    }
}

// GEMM2: att @ wT_proj + b_proj -> out (dtype per flag)
__global__ __launch_bounds__(256) void gemm_proj(
    const unsigned short* __restrict__ A,
    const unsigned short* __restrict__ Bt,
    const unsigned short* __restrict__ bias,
    const int* __restrict__ flag,
    void* __restrict__ outv)
{
    GEMM_PROLOG(A, Bt)
    const int isbf = *flag;
    const int gm0 = bm + wr * 64 + hi * 4;
#pragma unroll
    for (int m = 0; m < 4; ++m) {
        int gm = gm0 + m * 16;
#pragma unroll
        for (int n = 0; n < 4; ++n) {
            int col = bn + wc * 64 + n * 16 + lo;
            float bs = bf2f(bias[col]);
#pragma unroll
            for (int j = 0; j < 4; ++j) {
                float v = acc[m][n][j] + bs;
                if (isbf)
                    ((unsigned short*)outv)[(size_t)(gm + j) * 768 + col] = f2bf(v);
                else
                    ((float*)outv)[(size_t)(gm + j) * 768 + col] = v;
            }
        }
    }
}

// ---------------- flash attention (v6: swapped QK^T, lane-local softmax) ------
// mfma(K,Q) -> score[col=q=lane&15][row=kv=hi*4+j+nt*16]: each lane holds 16
// scores of ONE q-row -> row max/sum are 15 local VALU ops + 2 shfl_xor
// (was 8x 4-deep chains). Scores in log2 domain (Q pre-scaled by log2e),
// exp2f = bare v_exp_f32. P->LDS row=lo feeds the (verified) PV A-fragment
// read unchanged. Staging/pairing/grid identical to v5.
__global__ __launch_bounds__(256) void attn_fused(
    const unsigned short* __restrict__ q_ws,
    const unsigned short* __restrict__ k_ws,
    const unsigned short* __restrict__ v_ws,
    unsigned short* __restrict__ att)
{
    __shared__ __align__(16) unsigned short Kbuf[2][64 * 64];
    __shared__ __align__(16) unsigned short Vbuf[2][64 * 64];
    __shared__ __align__(16) unsigned short Pbuf[4][16 * 64];
    const int t = threadIdx.x;
    const int wave = t >> 6, lane = t & 63;
    const int lo = lane & 15, hi = lane >> 4;
    const int gid = blockIdx.x;
    const int xcd = gid & 7;
    const int c = gid >> 3;            // 0..95
    const int bh = xcd * 12 + (c % 12);
    const int pairIdx = c / 12;        // 0..7
    const int b_ = bh / 12, h = bh % 12;
    const size_t base = (size_t)bh * (1024 * 64);
    const unsigned short* Kb = k_ws + base;
    const unsigned short* Vb = v_ws + base;
    const float DEFER_THR = 11.5f;     // ~8 nats in log2 units

    // staging offsets: linear LDS dest (t*16B), pre-swizzled global source
    int L0 = t << 4, L1 = (t + 256) << 4;
    int S0 = L0 ^ (((L0 >> 7) & 7) << 4);
    int S1 = L1 ^ (((L1 >> 7) & 7) << 4);
    int r0 = S0 >> 7, o0 = (S0 & 127) >> 1;
    int r1 = S1 >> 7, o1 = (S1 & 127) >> 1;
    const int lof0 = (wave * 64) << 4;
    const int lof1 = (256 + wave * 64) << 4;

    // swizzled K/V fragment read offsets (128B rows, ^((row&7)<<4))
    int koff[4][2];
#pragma unroll
    for (int nt = 0; nt < 4; ++nt)
#pragma unroll
        for (int kc = 0; kc < 2; ++kc) {
            int P = ((nt * 16 + lo) << 7) + (kc << 6) + (hi << 4);
            koff[nt][kc] = P ^ (((P >> 7) & 7) << 4);
        }
    int poffR[2];
#pragma unroll
    for (int kc = 0; kc < 2; ++kc) {
        int P = (lo << 7) + (kc << 6) + (hi << 4);
        poffR[kc] = P ^ (((P >> 7) & 7) << 4);
    }
    // P write: row = lo (q-row), col = nt*16 + hi*4 + j (kv), same row-XOR
    int poffW[4][4];
#pragma unroll
    for (int nt = 0; nt < 4; ++nt)
#pragma unroll
        for (int j = 0; j < 4; ++j) {
            int P = (lo << 7) + ((nt * 16 + hi * 4 + j) << 1);
            poffW[nt][j] = P ^ ((lo & 7) << 4);
        }
    char* pb = (char*)&Pbuf[wave][0];

#pragma unroll 1
    for (int sel = 0; sel < 2; ++sel) {
        const int qt = sel ? pairIdx : (15 - pairIdx);
        const int q0w = qt * 64 + wave * 16;
        const int qrow = q0w + lo;     // this lane's q-row

        short8 qf[2];
#pragma unroll
        for (int kc = 0; kc < 2; ++kc)
            qf[kc] = *(const short8*)(q_ws + base +
                (size_t)(q0w + lo) * 64 + kc * 32 + hi * 8);

        f32x4 o[4];
        float mrun = -1e30f, lrun = 0.f;
#pragma unroll
        for (int nt = 0; nt < 4; ++nt) o[nt] = (f32x4){0.f, 0.f, 0.f, 0.f};

        if (sel) __syncthreads();
        glds16(Kb + (size_t)r0 * 64 + o0, (char*)Kbuf[0] + lof0);
        glds16(Kb + (size_t)r1 * 64 + o1, (char*)Kbuf[0] + lof1);
        glds16(Vb + (size_t)r0 * 1024 + o0, (char*)Vbuf[0] + lof0);
        glds16(Vb + (size_t)r1 * 1024 + o1, (char*)Vbuf[0] + lof1);

        int cur = 0;
        const int nkt = qt + 1;
        for (int kt = 0; kt < nkt; ++kt) {
            __syncthreads();  // staging of tile kt complete
            if (kt + 1 < nkt) {
                const int kn = (kt + 1) * 64;
                glds16(Kb + (size_t)(kn + r0) * 64 + o0, (char*)Kbuf[cur ^ 1] + lof0);
                glds16(Kb + (size_t)(kn + r1) * 64 + o1, (char*)Kbuf[cur ^ 1] + lof1);
                glds16(Vb + (size_t)r0 * 1024 + kn + o0, (char*)Vbuf[cur ^ 1] + lof0);
                glds16(Vb + (size_t)r1 * 1024 + kn + o1, (char*)Vbuf[cur ^ 1] + lof1);
            }
            const int kv0 = kt * 64;
            const char* Kc = (const char*)Kbuf[cur];
            const char* Vc = (const char*)Vbuf[cur];

            short8 kf[4][2];
#pragma unroll
            for (int nt = 0; nt < 4; ++nt)
#pragma unroll
                for (int kc = 0; kc < 2; ++kc)
                    kf[nt][kc] = *(const short8*)(Kc + koff[nt][kc]);
            // swapped: A=K, B=Q -> sc[nt] col=q(lo), rows=kv(hi*4+j)
            f32x4 sc[4];
            __builtin_amdgcn_s_setprio(1);
#pragma unroll
            for (int nt = 0; nt < 4; ++nt) {
                f32x4 z = (f32x4){0.f, 0.f, 0.f, 0.f};
                z = __builtin_amdgcn_mfma_f32_16x16x32_bf16(kf[nt][0], qf[0], z, 0, 0, 0);
                z = __builtin_amdgcn_mfma_f32_16x16x32_bf16(kf[nt][1], qf[1], z, 0, 0, 0);
                sc[nt] = z;
            }
            __builtin_amdgcn_s_setprio(0);
            if (kv0 + 63 > q0w) {
#pragma unroll
                for (int nt = 0; nt < 4; ++nt)
#pragma unroll
                    for (int j = 0; j < 4; ++j) {
                        int kc_ = kv0 + nt * 16 + hi * 4 + j;
                        if (kc_ > qrow) sc[nt][j] = -1e30f;
                    }
            }
            // lane-local row max (15 VALU) + 2 shfl across hi-groups
            float m0;
            {
                float a0 = fmaxf(fmaxf(sc[0][0], sc[0][1]), fmaxf(sc[0][2], sc[0][3]));
                float a1 = fmaxf(fmaxf(sc[1][0], sc[1][1]), fmaxf(sc[1][2], sc[1][3]));
                float a2 = fmaxf(fmaxf(sc[2][0], sc[2][1]), fmaxf(sc[2][2], sc[2][3]));
                float a3 = fmaxf(fmaxf(sc[3][0], sc[3][1]), fmaxf(sc[3][2], sc[3][3]));
                m0 = fmaxf(fmaxf(a0, a1), fmaxf(a2, a3));
            }
            m0 = fmaxf(m0, __shfl_xor(m0, 16));
            m0 = fmaxf(m0, __shfl_xor(m0, 32));
            // defer-max rescale
            if (__any(m0 > mrun + DEFER_THR)) {
                float nm = fmaxf(mrun, m0);
                float corr = __builtin_amdgcn_exp2f(mrun - nm);
                mrun = nm;
                lrun *= corr;
#pragma unroll
                for (int j = 0; j < 4; ++j) {
                    float cj = __shfl(corr, hi * 4 + j);
#pragma unroll
                    for (int nt = 0; nt < 4; ++nt) o[nt][j] *= cj;
                }
            }
            // exp2 + lane-local sum + 2 shfl
            float rs = 0.f;
#pragma unroll
            for (int nt = 0; nt < 4; ++nt)
#pragma unroll
                for (int j = 0; j < 4; ++j) {
                    float p = __builtin_amdgcn_exp2f(sc[nt][j] - mrun);
                    sc[nt][j] = p;
                    rs += p;
                }
            rs += __shfl_xor(rs, 16);
            rs += __shfl_xor(rs, 32);
            lrun += rs;
            // V fragments (hoisted)
            short8 vf[4][2];
#pragma unroll
            for (int nt = 0; nt < 4; ++nt)
#pragma unroll
                for (int kc2 = 0; kc2 < 2; ++kc2)
                    vf[nt][kc2] = *(const short8*)(Vc + koff[nt][kc2]);
            // P -> LDS (row = lo = q-row)
#pragma unroll
            for (int nt = 0; nt < 4; ++nt)
#pragma unroll
                for (int j = 0; j < 4; ++j)
                    *(unsigned short*)(pb + poffW[nt][j]) = f2bf(sc[nt][j]);
            // PV (unchanged: A-fragment reads P[q=lo][kv], O row=q(hi,j), col=d(lo))
#pragma unroll
            for (int kc2 = 0; kc2 < 2; ++kc2) {
                short8 pf = *(const short8*)(pb + poffR[kc2]);
                __builtin_amdgcn_s_setprio(1);
#pragma unroll
                for (int nt = 0; nt < 4; ++nt)
                    o[nt] = __builtin_amdgcn_mfma_f32_16x16x32_bf16(pf, vf[nt][kc2], o[nt], 0, 0, 0);
                __builtin_amdgcn_s_setprio(0);
            }
            cur ^= 1;
        }
        // epilogue: lrun for row hi*4+j lives at lane (hi*4+j)
#pragma unroll
        for (int j = 0; j < 4; ++j) {
            float lj = __shfl(lrun, hi * 4 + j);
            float inv = 1.f / lj;
            int tt = q0w + hi * 4 + j;
#pragma unroll
            for (int nt = 0; nt < 4; ++nt)
                att[((size_t)(b_ * 1024 + tt)) * 768 + h * 64 + nt * 16 + lo] =
                    f2bf(o[nt][j] * inv);
        }
    }
}

extern "C" void kernel_launch(void* const* d_in, const int* in_sizes, int n_in,
                              void* d_out, int out_size, void* d_ws, size_t ws_size,
                              hipStream_t stream) {
    const void* x      = d_in[0];
    const void* w_attn = d_in[1];
    const void* b_attn = d_in[2];
    const void* w_proj = d_in[3];
    const void* b_proj = d_in[4];
    const void* rel    = d_in[5];
    char* ws = (char*)d_ws;
    int*            flag = (int*)(ws + 0);
    unsigned short* wTa  = (unsigned short*)(ws + 4096);
    unsigned short* wTp  = (unsigned short*)(ws + 3543040);
    unsigned short* x_bf = (unsigned short*)(ws + 4722688);
    unsigned short* relb = (unsigned short*)(ws + 17305600);
    unsigned short* bab  = (unsigned short*)(ws + 17567616);
    unsigned short* bpb  = (unsigned short*)(ws + 17572224);
    unsigned short* q_ws = (unsigned short*)(ws + 17573760);
    unsigned short* k_ws = (unsigned short*)(ws + 30156672);
    unsigned short* v_ws = (unsigned short*)(ws + 42739584);
    unsigned short* att  = x_bf;  // reuse: x_bf dead after gemm_qkv

    detect_dtype<<<1, 256, 0, stream>>>((const unsigned int*)w_attn, flag);
    cast_x<<<6144, 256, 0, stream>>>(x, x_bf, flag);
    cast_small<<<524, 256, 0, stream>>>(rel, b_attn, b_proj, relb, bab, bpb, flag);
    transpose_w<<<dim3(36, 12), 256, 0, stream>>>(w_attn, wTa, 768, 2304, flag);
    transpose_w<<<dim3(12, 12), 256, 0, stream>>>(w_proj, wTp, 768, 768, flag);
    gemm_qkv<<<dim3(64, 18), 256, 0, stream>>>(x_bf, wTa, bab, relb, q_ws, k_ws, v_ws);
    attn_fused<<<768, 256, 0, stream>>>(q_ws, k_ws, v_ws, att);
    gemm_proj<<<dim3(64, 6), 256, 0, stream>>>(att, wTp, bpb, flag, (void*)d_out);
}

// Round 9
// 214.236 us; speedup vs baseline: 1.3158x; 1.0036x over previous
//
#include <hip/hip_runtime.h>
#include <stdint.h>

// Pipeline: detect dtype -> cast inputs to bf16 -> transpose weights ->
//   GEMM1(x @ w_attn^T, scatter Q*scale*log2e / K+rel / V^T) -> flash attention
//   (swapped-QK^T lane-local softmax, log2-domain) -> GEMM2 (+b_proj) -> out
// R8: both GEMMs now use double-buffered staging with ONE barrier per K-step
// (prefetch next tile right after the barrier, compute current underneath) --
// same schedule that cut attn 25% in R6.

typedef __attribute__((ext_vector_type(8))) short short8;
typedef __attribute__((ext_vector_type(4))) float f32x4;
typedef __attribute__((ext_vector_type(4))) unsigned short ushort4v;

#define DEV static __device__ __forceinline__

DEV float bf2f(unsigned short u) {
    union { unsigned int u; float f; } v; v.u = ((unsigned int)u) << 16; return v.f;
}
DEV unsigned short f2bf(float f) {
    union { float f; unsigned int u; } v; v.f = f;
    unsigned int u = v.u;
    return (unsigned short)((u + 0x7fffu + ((u >> 16) & 1u)) >> 16);
}

typedef const __attribute__((address_space(1))) void* gas_ptr;
typedef __attribute__((address_space(3))) void* las_ptr;
DEV void glds16(const void* g, void* l) {
    __builtin_amdgcn_global_load_lds((gas_ptr)g, (las_ptr)l, 16, 0, 0);
}

// ---------------- dtype detector ----------------
__global__ void detect_dtype(const unsigned int* __restrict__ w, int* __restrict__ flag) {
    __shared__ int cnt;
    if (threadIdx.x == 0) cnt = 0;
    __syncthreads();
    int c = 0;
    for (int i = threadIdx.x; i < 8192; i += 256) {
        unsigned int b1 = (w[i] >> 8) & 0x7F;
        c += (b1 >= 0x38 && b1 <= 0x3E) ? 1 : 0;
    }
    atomicAdd(&cnt, c);
    __syncthreads();
    if (threadIdx.x == 0) *flag = (cnt > 4096) ? 1 : 0;  // 1 = bf16 inputs
}

// ---------------- casts ----------------
__global__ __launch_bounds__(256) void cast_x(
    const void* __restrict__ x, unsigned short* __restrict__ xo,
    const int* __restrict__ flag)
{
    int i = (blockIdx.x * 256 + threadIdx.x) * 4;
    if (*flag) {
        *(ushort4v*)(xo + i) = *(const ushort4v*)((const unsigned short*)x + i);
    } else {
        f32x4 v = *(const f32x4*)((const float*)x + i);
        ushort4v o;
#pragma unroll
        for (int j = 0; j < 4; ++j) o[j] = f2bf(v[j]);
        *(ushort4v*)(xo + i) = o;
    }
}

__global__ __launch_bounds__(256) void cast_small(
    const void* __restrict__ rel, const void* __restrict__ ba, const void* __restrict__ bp,
    unsigned short* __restrict__ rel_o, unsigned short* __restrict__ ba_o,
    unsigned short* __restrict__ bp_o, const int* __restrict__ flag)
{
    int i = blockIdx.x * 256 + threadIdx.x;
    if (i >= 134080) return;
    int isbf = *flag;
    const void* src; unsigned short* dst; int off;
    if (i < 131008)      { src = rel; dst = rel_o; off = i; }
    else if (i < 133312) { src = ba;  dst = ba_o;  off = i - 131008; }
    else                 { src = bp;  dst = bp_o;  off = i - 133312; }
    dst[off] = isbf ? ((const unsigned short*)src)[off]
                    : f2bf(((const float*)src)[off]);
}

// ---------------- weight transpose (either dtype in, bf16 out), 64x64 tiles ----
__global__ __launch_bounds__(256) void transpose_w(
    const void* __restrict__ in, unsigned short* __restrict__ out,
    int R, int C, const int* __restrict__ flag)
{
    __shared__ unsigned short tile[64][66];
    const int t = threadIdx.x;
    const int cb = blockIdx.x * 64;
    const int rb = blockIdx.y * 64;
    if (*flag) {
        const unsigned short* inp = (const unsigned short*)in;
        const int c8 = (t & 7) * 8;
        const int r = t >> 3;
#pragma unroll
        for (int p = 0; p < 2; ++p) {
            int rr = r + p * 32;
            short8 v = *(const short8*)(inp + (size_t)(rb + rr) * C + cb + c8);
#pragma unroll
            for (int i = 0; i < 8; ++i) tile[rr][c8 + i] = (unsigned short)v[i];
        }
    } else {
        const float* inp = (const float*)in;
        const int c4 = (t & 15) * 4;
        const int r = t >> 4;
#pragma unroll
        for (int p = 0; p < 4; ++p) {
            int rr = r + p * 16;
            f32x4 v = *(const f32x4*)(inp + (size_t)(rb + rr) * C + cb + c4);
#pragma unroll
            for (int i = 0; i < 4; ++i) tile[rr][c4 + i] = f2bf(v[i]);
        }
    }
    __syncthreads();
    {
        const int c8 = (t & 7) * 8;
        const int r = t >> 3;
#pragma unroll
        for (int p = 0; p < 2; ++p) {
            int oc = r + p * 32;
            short8 v;
#pragma unroll
            for (int i = 0; i < 8; ++i) v[i] = (short)tile[c8 + i][oc];
            *(short8*)(out + (size_t)(cb + oc) * R + rb + c8) = v;
        }
    }
}

// ------- GEMM skeleton: 128x128 tile, BK=32, 4 waves, DBUF + 1 barrier/iter ---
// A [M][768] row-major bf16, Bt [N][768] row-major bf16 (pre-transposed).
// LDS swizzle (64B rows): addr ^= ((addr>>7)&3)<<4  (involution)
#define GEMM_PROLOG(A_, Bt_)                                                     \
    __shared__ __align__(16) unsigned short Abuf[2][128 * 32];                   \
    __shared__ __align__(16) unsigned short Bbuf[2][128 * 32];                   \
    const int t = threadIdx.x;                                                   \
    const int wave = t >> 6, lane = t & 63;                                      \
    const int lo = lane & 15, hi = lane >> 4;                                    \
    const int wr = wave >> 1, wc = wave & 1;                                     \
    const int bm = blockIdx.x * 128;                                             \
    const int bn = blockIdx.y * 128;                                             \
    int L0 = t << 4, L1 = (t + 256) << 4;                                        \
    int S0 = L0 ^ (((L0 >> 7) & 3) << 4);                                        \
    int S1 = L1 ^ (((L1 >> 7) & 3) << 4);                                        \
    int r0 = S0 >> 6, o0 = (S0 & 63) >> 1;                                       \
    int r1 = S1 >> 6, o1 = (S1 & 63) >> 1;                                       \
    const unsigned short* Ab = (A_) + (size_t)bm * 768;                          \
    const unsigned short* Bb = (Bt_) + (size_t)bn * 768;                         \
    const int lof0 = (wave * 64) << 4;                                           \
    const int lof1 = (256 + wave * 64) << 4;                                     \
    int aoff[4]; int boff[4];                                                    \
    _Pragma("unroll")                                                            \
    for (int m = 0; m < 4; ++m) {                                                \
        int Pa = ((wr * 64 + m * 16 + lo) << 6) + (hi << 4);                     \
        aoff[m] = Pa ^ (((Pa >> 7) & 3) << 4);                                   \
        int Pb = ((wc * 64 + m * 16 + lo) << 6) + (hi << 4);                     \
        boff[m] = Pb ^ (((Pb >> 7) & 3) << 4);                                   \
    }                                                                            \
    f32x4 acc[4][4];                                                             \
    _Pragma("unroll")                                                            \
    for (int m = 0; m < 4; ++m)                                                  \
        _Pragma("unroll")                                                        \
        for (int n = 0; n < 4; ++n) acc[m][n] = (f32x4){0.f, 0.f, 0.f, 0.f};     \
    /* prologue: stage k0=0 into buffer 0 */                                     \
    glds16(Ab + (size_t)r0 * 768 + o0, (char*)Abuf[0] + lof0);                   \
    glds16(Ab + (size_t)r1 * 768 + o1, (char*)Abuf[0] + lof1);                   \
    glds16(Bb + (size_t)r0 * 768 + o0, (char*)Bbuf[0] + lof0);                   \
    glds16(Bb + (size_t)r1 * 768 + o1, (char*)Bbuf[0] + lof1);                   \
    int cur = 0;                                                                 \
    for (int k0 = 0; k0 < 768; k0 += 32) {                                       \
        __syncthreads();  /* staging of tile k0 complete (vmcnt drained) */      \
        if (k0 + 32 < 768) {                                                     \
            const int kn = k0 + 32;                                              \
            glds16(Ab + (size_t)r0 * 768 + kn + o0, (char*)Abuf[cur ^ 1] + lof0);\
            glds16(Ab + (size_t)r1 * 768 + kn + o1, (char*)Abuf[cur ^ 1] + lof1);\
            glds16(Bb + (size_t)r0 * 768 + kn + o0, (char*)Bbuf[cur ^ 1] + lof0);\
            glds16(Bb + (size_t)r1 * 768 + kn + o1, (char*)Bbuf[cur ^ 1] + lof1);\
        }                                                                        \
        short8 af[4], bfv[4];                                                    \
        _Pragma("unroll")                                                        \
        for (int m = 0; m < 4; ++m)                                              \
            af[m] = *(const short8*)((const char*)Abuf[cur] + aoff[m]);          \
        _Pragma("unroll")                                                        \
        for (int n = 0; n < 4; ++n)                                              \
            bfv[n] = *(const short8*)((const char*)Bbuf[cur] + boff[n]);         \
        _Pragma("unroll")                                                        \
        for (int m = 0; m < 4; ++m)                                              \
            _Pragma("unroll")                                                    \
            for (int n = 0; n < 4; ++n)                                          \
                acc[m][n] = __builtin_amdgcn_mfma_f32_16x16x32_bf16(             \
                    af[m], bfv[n], acc[m][n], 0, 0, 0);                          \
        cur ^= 1;                                                                \
    }

// GEMM1: epilogue scatters q (scale*log2e folded), k (+rel), v (transposed)
__global__ __launch_bounds__(256) void gemm_qkv(
    const unsigned short* __restrict__ A,
    const unsigned short* __restrict__ Bt,
    const unsigned short* __restrict__ bias,
    const unsigned short* __restrict__ rel,
    unsigned short* __restrict__ q_ws,
    unsigned short* __restrict__ k_ws,
    unsigned short* __restrict__ v_ws)
{
    GEMM_PROLOG(A, Bt)
    const int gm0 = bm + wr * 64 + hi * 4;
    const float QSCALE = 0.125f * 1.44269504f;  // fold log2e: scores in log2 units
#pragma unroll
    for (int m = 0; m < 4; ++m) {
        int gm = gm0 + m * 16;
        int b_ = gm >> 10;
        int tt = gm & 1023;
#pragma unroll
        for (int n = 0; n < 4; ++n) {
            int col = bn + wc * 64 + n * 16 + lo;
            float bs = bf2f(bias[col]);
            if (col < 768) {
                int h = col >> 6, d = col & 63;
                size_t base = (((size_t)b_ * 12 + h) * 1024 + tt) * 64 + d;
#pragma unroll
                for (int j = 0; j < 4; ++j)
                    q_ws[base + (size_t)j * 64] = f2bf((acc[m][n][j] + bs) * QSCALE);
            } else if (col < 1536) {
                int h = (col - 768) >> 6, d = col & 63;
                size_t base = (((size_t)b_ * 12 + h) * 1024 + tt) * 64 + d;
#pragma unroll
                for (int j = 0; j < 4; ++j) {
                    int trow = tt + j;
                    float rv = (trow > 0) ? bf2f(rel[(size_t)(trow - 1) * 64 + d]) : 0.f;
                    k_ws[base + (size_t)j * 64] = f2bf(acc[m][n][j] + bs + rv);
                }
            } else {
                int h = (col - 1536) >> 6, d = col & 63;
                size_t vb = (((size_t)b_ * 12 + h) * 64 + d) * 1024 + tt;
                ushort4v pk;
#pragma unroll
                for (int j = 0; j < 4; ++j) pk[j] = f2bf(acc[m][n][j] + bs);
                *(ushort4v*)(v_ws + vb) = pk;
            }
        }
    }
}

// GEMM2: att @ wT_proj + b_proj -> out (dtype per flag)
__global__ __launch_bounds__(256) void gemm_proj(
    const unsigned short* __restrict__ A,
    const unsigned short* __restrict__ Bt,
    const unsigned short* __restrict__ bias,
    const int* __restrict__ flag,
    void* __restrict__ outv)
{
    GEMM_PROLOG(A, Bt)
    const int isbf = *flag;
    const int gm0 = bm + wr * 64 + hi * 4;
#pragma unroll
    for (int m = 0; m < 4; ++m) {
        int gm = gm0 + m * 16;
#pragma unroll
        for (int n = 0; n < 4; ++n) {
            int col = bn + wc * 64 + n * 16 + lo;
            float bs = bf2f(bias[col]);
#pragma unroll
            for (int j = 0; j < 4; ++j) {
                float v = acc[m][n][j] + bs;
                if (isbf)
                    ((unsigned short*)outv)[(size_t)(gm + j) * 768 + col] = f2bf(v);
                else
                    ((float*)outv)[(size_t)(gm + j) * 768 + col] = v;
            }
        }
    }
}

// ---------------- flash attention (v6: swapped QK^T, lane-local softmax) ------
__global__ __launch_bounds__(256) void attn_fused(
    const unsigned short* __restrict__ q_ws,
    const unsigned short* __restrict__ k_ws,
    const unsigned short* __restrict__ v_ws,
    unsigned short* __restrict__ att)
{
    __shared__ __align__(16) unsigned short Kbuf[2][64 * 64];
    __shared__ __align__(16) unsigned short Vbuf[2][64 * 64];
    __shared__ __align__(16) unsigned short Pbuf[4][16 * 64];
    const int t = threadIdx.x;
    const int wave = t >> 6, lane = t & 63;
    const int lo = lane & 15, hi = lane >> 4;
    const int gid = blockIdx.x;
    const int xcd = gid & 7;
    const int c = gid >> 3;            // 0..95
    const int bh = xcd * 12 + (c % 12);
    const int pairIdx = c / 12;        // 0..7
    const int b_ = bh / 12, h = bh % 12;
    const size_t base = (size_t)bh * (1024 * 64);
    const unsigned short* Kb = k_ws + base;
    const unsigned short* Vb = v_ws + base;
    const float DEFER_THR = 11.5f;     // ~8 nats in log2 units

    int L0 = t << 4, L1 = (t + 256) << 4;
    int S0 = L0 ^ (((L0 >> 7) & 7) << 4);
    int S1 = L1 ^ (((L1 >> 7) & 7) << 4);
    int r0 = S0 >> 7, o0 = (S0 & 127) >> 1;
    int r1 = S1 >> 7, o1 = (S1 & 127) >> 1;
    const int lof0 = (wave * 64) << 4;
    const int lof1 = (256 + wave * 64) << 4;

    int koff[4][2];
#pragma unroll
    for (int nt = 0; nt < 4; ++nt)
#pragma unroll
        for (int kc = 0; kc < 2; ++kc) {
            int P = ((nt * 16 + lo) << 7) + (kc << 6) + (hi << 4);
            koff[nt][kc] = P ^ (((P >> 7) & 7) << 4);
        }
    int poffR[2];
#pragma unroll
    for (int kc = 0; kc < 2; ++kc) {
        int P = (lo << 7) + (kc << 6) + (hi << 4);
        poffR[kc] = P ^ (((P >> 7) & 7) << 4);
    }
    int poffW[4][4];
#pragma unroll
    for (int nt = 0; nt < 4; ++nt)
#pragma unroll
        for (int j = 0; j < 4; ++j) {
            int P = (lo << 7) + ((nt * 16 + hi * 4 + j) << 1);
            poffW[nt][j] = P ^ ((lo & 7) << 4);
        }
    char* pb = (char*)&Pbuf[wave][0];

#pragma unroll 1
    for (int sel = 0; sel < 2; ++sel) {
        const int qt = sel ? pairIdx : (15 - pairIdx);
        const int q0w = qt * 64 + wave * 16;
        const int qrow = q0w + lo;     // this lane's q-row

        short8 qf[2];
#pragma unroll
        for (int kc = 0; kc < 2; ++kc)
            qf[kc] = *(const short8*)(q_ws + base +
                (size_t)(q0w + lo) * 64 + kc * 32 + hi * 8);

        f32x4 o[4];
        float mrun = -1e30f, lrun = 0.f;
#pragma unroll
        for (int nt = 0; nt < 4; ++nt) o[nt] = (f32x4){0.f, 0.f, 0.f, 0.f};

        if (sel) __syncthreads();
        glds16(Kb + (size_t)r0 * 64 + o0, (char*)Kbuf[0] + lof0);
        glds16(Kb + (size_t)r1 * 64 + o1, (char*)Kbuf[0] + lof1);
        glds16(Vb + (size_t)r0 * 1024 + o0, (char*)Vbuf[0] + lof0);
        glds16(Vb + (size_t)r1 * 1024 + o1, (char*)Vbuf[0] + lof1);

        int cur = 0;
        const int nkt = qt + 1;
        for (int kt = 0; kt < nkt; ++kt) {
            __syncthreads();  // staging of tile kt complete
            if (kt + 1 < nkt) {
                const int kn = (kt + 1) * 64;
                glds16(Kb + (size_t)(kn + r0) * 64 + o0, (char*)Kbuf[cur ^ 1] + lof0);
                glds16(Kb + (size_t)(kn + r1) * 64 + o1, (char*)Kbuf[cur ^ 1] + lof1);
                glds16(Vb + (size_t)r0 * 1024 + kn + o0, (char*)Vbuf[cur ^ 1] + lof0);
                glds16(Vb + (size_t)r1 * 1024 + kn + o1, (char*)Vbuf[cur ^ 1] + lof1);
            }
            const int kv0 = kt * 64;
            const char* Kc = (const char*)Kbuf[cur];
            const char* Vc = (const char*)Vbuf[cur];

            short8 kf[4][2];
#pragma unroll
            for (int nt = 0; nt < 4; ++nt)
#pragma unroll
                for (int kc = 0; kc < 2; ++kc)
                    kf[nt][kc] = *(const short8*)(Kc + koff[nt][kc]);
            // swapped: A=K, B=Q -> sc[nt] col=q(lo), rows=kv(hi*4+j)
            f32x4 sc[4];
            __builtin_amdgcn_s_setprio(1);
#pragma unroll
            for (int nt = 0; nt < 4; ++nt) {
                f32x4 z = (f32x4){0.f, 0.f, 0.f, 0.f};
                z = __builtin_amdgcn_mfma_f32_16x16x32_bf16(kf[nt][0], qf[0], z, 0, 0, 0);
                z = __builtin_amdgcn_mfma_f32_16x16x32_bf16(kf[nt][1], qf[1], z, 0, 0, 0);
                sc[nt] = z;
            }
            __builtin_amdgcn_s_setprio(0);
            if (kv0 + 63 > q0w) {
#pragma unroll
                for (int nt = 0; nt < 4; ++nt)
#pragma unroll
                    for (int j = 0; j < 4; ++j) {
                        int kc_ = kv0 + nt * 16 + hi * 4 + j;
                        if (kc_ > qrow) sc[nt][j] = -1e30f;
                    }
            }
            // lane-local row max (15 VALU) + 2 shfl across hi-groups
            float m0;
            {
                float a0 = fmaxf(fmaxf(sc[0][0], sc[0][1]), fmaxf(sc[0][2], sc[0][3]));
                float a1 = fmaxf(fmaxf(sc[1][0], sc[1][1]), fmaxf(sc[1][2], sc[1][3]));
                float a2 = fmaxf(fmaxf(sc[2][0], sc[2][1]), fmaxf(sc[2][2], sc[2][3]));
                float a3 = fmaxf(fmaxf(sc[3][0], sc[3][1]), fmaxf(sc[3][2], sc[3][3]));
                m0 = fmaxf(fmaxf(a0, a1), fmaxf(a2, a3));
            }
            m0 = fmaxf(m0, __shfl_xor(m0, 16));
            m0 = fmaxf(m0, __shfl_xor(m0, 32));
            // defer-max rescale
            if (__any(m0 > mrun + DEFER_THR)) {
                float nm = fmaxf(mrun, m0);
                float corr = __builtin_amdgcn_exp2f(mrun - nm);
                mrun = nm;
                lrun *= corr;
#pragma unroll
                for (int j = 0; j < 4; ++j) {
                    float cj = __shfl(corr, hi * 4 + j);
#pragma unroll
                    for (int nt = 0; nt < 4; ++nt) o[nt][j] *= cj;
                }
            }
            // exp2 + lane-local sum + 2 shfl
            float rs = 0.f;
#pragma unroll
            for (int nt = 0; nt < 4; ++nt)
#pragma unroll
                for (int j = 0; j < 4; ++j) {
                    float p = __builtin_amdgcn_exp2f(sc[nt][j] - mrun);
                    sc[nt][j] = p;
                    rs += p;
                }
            rs += __shfl_xor(rs, 16);
            rs += __shfl_xor(rs, 32);
            lrun += rs;
            // V fragments (hoisted)
            short8 vf[4][2];
#pragma unroll
            for (int nt = 0; nt < 4; ++nt)
#pragma unroll
                for (int kc2 = 0; kc2 < 2; ++kc2)
                    vf[nt][kc2] = *(const short8*)(Vc + koff[nt][kc2]);
            // P -> LDS (row = lo = q-row)
#pragma unroll
            for (int nt = 0; nt < 4; ++nt)
#pragma unroll
                for (int j = 0; j < 4; ++j)
                    *(unsigned short*)(pb + poffW[nt][j]) = f2bf(sc[nt][j]);
            // PV
#pragma unroll
            for (int kc2 = 0; kc2 < 2; ++kc2) {
                short8 pf = *(const short8*)(pb + poffR[kc2]);
                __builtin_amdgcn_s_setprio(1);
#pragma unroll
                for (int nt = 0; nt < 4; ++nt)
                    o[nt] = __builtin_amdgcn_mfma_f32_16x16x32_bf16(pf, vf[nt][kc2], o[nt], 0, 0, 0);
                __builtin_amdgcn_s_setprio(0);
            }
            cur ^= 1;
        }
        // epilogue: lrun for row hi*4+j lives at lane (hi*4+j)
#pragma unroll
        for (int j = 0; j < 4; ++j) {
            float lj = __shfl(lrun, hi * 4 + j);
            float inv = 1.f / lj;
            int tt = q0w + hi * 4 + j;
#pragma unroll
            for (int nt = 0; nt < 4; ++nt)
                att[((size_t)(b_ * 1024 + tt)) * 768 + h * 64 + nt * 16 + lo] =
                    f2bf(o[nt][j] * inv);
        }
    }
}

extern "C" void kernel_launch(void* const* d_in, const int* in_sizes, int n_in,
                              void* d_out, int out_size, void* d_ws, size_t ws_size,
                              hipStream_t stream) {
    const void* x      = d_in[0];
    const void* w_attn = d_in[1];
    const void* b_attn = d_in[2];
    const void* w_proj = d_in[3];
    const void* b_proj = d_in[4];
    const void* rel    = d_in[5];
    char* ws = (char*)d_ws;
    int*            flag = (int*)(ws + 0);
    unsigned short* wTa  = (unsigned short*)(ws + 4096);
    unsigned short* wTp  = (unsigned short*)(ws + 3543040);
    unsigned short* x_bf = (unsigned short*)(ws + 4722688);
    unsigned short* relb = (unsigned short*)(ws + 17305600);
    unsigned short* bab  = (unsigned short*)(ws + 17567616);
    unsigned short* bpb  = (unsigned short*)(ws + 17572224);
    unsigned short* q_ws = (unsigned short*)(ws + 17573760);
    unsigned short* k_ws = (unsigned short*)(ws + 30156672);
    unsigned short* v_ws = (unsigned short*)(ws + 42739584);
    unsigned short* att  = x_bf;  // reuse: x_bf dead after gemm_qkv

    detect_dtype<<<1, 256, 0, stream>>>((const unsigned int*)w_attn, flag);
    cast_x<<<6144, 256, 0, stream>>>(x, x_bf, flag);
    cast_small<<<524, 256, 0, stream>>>(rel, b_attn, b_proj, relb, bab, bpb, flag);
    transpose_w<<<dim3(36, 12), 256, 0, stream>>>(w_attn, wTa, 768, 2304, flag);
    transpose_w<<<dim3(12, 12), 256, 0, stream>>>(w_proj, wTp, 768, 768, flag);
    gemm_qkv<<<dim3(64, 18), 256, 0, stream>>>(x_bf, wTa, bab, relb, q_ws, k_ws, v_ws);
    attn_fused<<<768, 256, 0, stream>>>(q_ws, k_ws, v_ws, att);
    gemm_proj<<<dim3(64, 6), 256, 0, stream>>>(att, wTp, bpb, flag, (void*)d_out);
}

// Round 10
// 206.060 us; speedup vs baseline: 1.3680x; 1.0397x over previous
//
#include <hip/hip_runtime.h>
#include <stdint.h>

// Pipeline: detect dtype -> cast inputs to bf16 -> transpose weights ->
//   GEMM1(x @ w_attn^T, scatter Q*scale*log2e / K+rel / V^T) -> flash attention
//   (swapped-QK^T lane-local softmax, log2-domain) -> GEMM2 (+b_proj) -> out
// R10: GEMMs use 3-buffer LDS pipeline with COUNTED vmcnt(4) (2 tiles in
// flight across raw s_barrier; wait-before-barrier per m201 pattern).

typedef __attribute__((ext_vector_type(8))) short short8;
typedef __attribute__((ext_vector_type(4))) float f32x4;
typedef __attribute__((ext_vector_type(4))) unsigned short ushort4v;

#define DEV static __device__ __forceinline__

DEV float bf2f(unsigned short u) {
    union { unsigned int u; float f; } v; v.u = ((unsigned int)u) << 16; return v.f;
}
DEV unsigned short f2bf(float f) {
    union { float f; unsigned int u; } v; v.f = f;
    unsigned int u = v.u;
    return (unsigned short)((u + 0x7fffu + ((u >> 16) & 1u)) >> 16);
}

typedef const __attribute__((address_space(1))) void* gas_ptr;
typedef __attribute__((address_space(3))) void* las_ptr;
DEV void glds16(const void* g, void* l) {
    __builtin_amdgcn_global_load_lds((gas_ptr)g, (las_ptr)l, 16, 0, 0);
}

// ---------------- dtype detector ----------------
__global__ void detect_dtype(const unsigned int* __restrict__ w, int* __restrict__ flag) {
    __shared__ int cnt;
    if (threadIdx.x == 0) cnt = 0;
    __syncthreads();
    int c = 0;
    for (int i = threadIdx.x; i < 8192; i += 256) {
        unsigned int b1 = (w[i] >> 8) & 0x7F;
        c += (b1 >= 0x38 && b1 <= 0x3E) ? 1 : 0;
    }
    atomicAdd(&cnt, c);
    __syncthreads();
    if (threadIdx.x == 0) *flag = (cnt > 4096) ? 1 : 0;  // 1 = bf16 inputs
}

// ---------------- casts ----------------
__global__ __launch_bounds__(256) void cast_x(
    const void* __restrict__ x, unsigned short* __restrict__ xo,
    const int* __restrict__ flag)
{
    int i = (blockIdx.x * 256 + threadIdx.x) * 4;
    if (*flag) {
        *(ushort4v*)(xo + i) = *(const ushort4v*)((const unsigned short*)x + i);
    } else {
        f32x4 v = *(const f32x4*)((const float*)x + i);
        ushort4v o;
#pragma unroll
        for (int j = 0; j < 4; ++j) o[j] = f2bf(v[j]);
        *(ushort4v*)(xo + i) = o;
    }
}

__global__ __launch_bounds__(256) void cast_small(
    const void* __restrict__ rel, const void* __restrict__ ba, const void* __restrict__ bp,
    unsigned short* __restrict__ rel_o, unsigned short* __restrict__ ba_o,
    unsigned short* __restrict__ bp_o, const int* __restrict__ flag)
{
    int i = blockIdx.x * 256 + threadIdx.x;
    if (i >= 134080) return;
    int isbf = *flag;
    const void* src; unsigned short* dst; int off;
    if (i < 131008)      { src = rel; dst = rel_o; off = i; }
    else if (i < 133312) { src = ba;  dst = ba_o;  off = i - 131008; }
    else                 { src = bp;  dst = bp_o;  off = i - 133312; }
    dst[off] = isbf ? ((const unsigned short*)src)[off]
                    : f2bf(((const float*)src)[off]);
}

// ---------------- weight transpose (either dtype in, bf16 out), 64x64 tiles ----
__global__ __launch_bounds__(256) void transpose_w(
    const void* __restrict__ in, unsigned short* __restrict__ out,
    int R, int C, const int* __restrict__ flag)
{
    __shared__ unsigned short tile[64][66];
    const int t = threadIdx.x;
    const int cb = blockIdx.x * 64;
    const int rb = blockIdx.y * 64;
    if (*flag) {
        const unsigned short* inp = (const unsigned short*)in;
        const int c8 = (t & 7) * 8;
        const int r = t >> 3;
#pragma unroll
        for (int p = 0; p < 2; ++p) {
            int rr = r + p * 32;
            short8 v = *(const short8*)(inp + (size_t)(rb + rr) * C + cb + c8);
#pragma unroll
            for (int i = 0; i < 8; ++i) tile[rr][c8 + i] = (unsigned short)v[i];
        }
    } else {
        const float* inp = (const float*)in;
        const int c4 = (t & 15) * 4;
        const int r = t >> 4;
#pragma unroll
        for (int p = 0; p < 4; ++p) {
            int rr = r + p * 16;
            f32x4 v = *(const f32x4*)(inp + (size_t)(rb + rr) * C + cb + c4);
#pragma unroll
            for (int i = 0; i < 4; ++i) tile[rr][c4 + i] = f2bf(v[i]);
        }
    }
    __syncthreads();
    {
        const int c8 = (t & 7) * 8;
        const int r = t >> 3;
#pragma unroll
        for (int p = 0; p < 2; ++p) {
            int oc = r + p * 32;
            short8 v;
#pragma unroll
            for (int i = 0; i < 8; ++i) v[i] = (short)tile[c8 + i][oc];
            *(short8*)(out + (size_t)(cb + oc) * R + rb + c8) = v;
        }
    }
}

// -- GEMM skeleton: 128x128 tile, BK=32, 4 waves, 3-buf + counted vmcnt(4) ----
// A [M][768] row-major bf16, Bt [N][768] row-major bf16 (pre-transposed).
// LDS swizzle (64B rows): addr ^= ((addr>>7)&3)<<4  (involution).
// Schedule per K-step t: wait vmcnt(4) [tile t landed, tile t+1 in flight]
//   -> s_barrier -> issue stage(t+2) -> ds_read tile t -> 16 MFMA.
// Wait-BEFORE-barrier: barrier release implies every wave's tile-t loads
// retired. Slot (t+2)%3 was fully consumed before this barrier (lgkm waits
// precede each wave's MFMAs, which precede its barrier arrival).
#define GEMM_STAGE(kk, sl)                                                       \
    glds16(Ab + (size_t)r0 * 768 + (kk) + o0, (char*)Abuf[sl] + lof0);           \
    glds16(Ab + (size_t)r1 * 768 + (kk) + o1, (char*)Abuf[sl] + lof1);           \
    glds16(Bb + (size_t)r0 * 768 + (kk) + o0, (char*)Bbuf[sl] + lof0);           \
    glds16(Bb + (size_t)r1 * 768 + (kk) + o1, (char*)Bbuf[sl] + lof1);

#define GEMM_PROLOG(A_, Bt_)                                                     \
    __shared__ __align__(16) unsigned short Abuf[3][128 * 32];                   \
    __shared__ __align__(16) unsigned short Bbuf[3][128 * 32];                   \
    const int t = threadIdx.x;                                                   \
    const int wave = t >> 6, lane = t & 63;                                      \
    const int lo = lane & 15, hi = lane >> 4;                                    \
    const int wr = wave >> 1, wc = wave & 1;                                     \
    const int bm = blockIdx.x * 128;                                             \
    const int bn = blockIdx.y * 128;                                             \
    int L0 = t << 4, L1 = (t + 256) << 4;                                        \
    int S0 = L0 ^ (((L0 >> 7) & 3) << 4);                                        \
    int S1 = L1 ^ (((L1 >> 7) & 3) << 4);                                        \
    int r0 = S0 >> 6, o0 = (S0 & 63) >> 1;                                       \
    int r1 = S1 >> 6, o1 = (S1 & 63) >> 1;                                       \
    const unsigned short* Ab = (A_) + (size_t)bm * 768;                          \
    const unsigned short* Bb = (Bt_) + (size_t)bn * 768;                         \
    const int lof0 = (wave * 64) << 4;                                           \
    const int lof1 = (256 + wave * 64) << 4;                                     \
    int aoff[4]; int boff[4];                                                    \
    _Pragma("unroll")                                                            \
    for (int m = 0; m < 4; ++m) {                                                \
        int Pa = ((wr * 64 + m * 16 + lo) << 6) + (hi << 4);                     \
        aoff[m] = Pa ^ (((Pa >> 7) & 3) << 4);                                   \
        int Pb = ((wc * 64 + m * 16 + lo) << 6) + (hi << 4);                     \
        boff[m] = Pb ^ (((Pb >> 7) & 3) << 4);                                   \
    }                                                                            \
    f32x4 acc[4][4];                                                             \
    _Pragma("unroll")                                                            \
    for (int m = 0; m < 4; ++m)                                                  \
        _Pragma("unroll")                                                        \
        for (int n = 0; n < 4; ++n) acc[m][n] = (f32x4){0.f, 0.f, 0.f, 0.f};     \
    GEMM_STAGE(0, 0)                                                             \
    GEMM_STAGE(32, 1)                                                            \
    _Pragma("unroll")                                                            \
    for (int kt_ = 0; kt_ < 24; ++kt_) {                                         \
        if (kt_ < 23) { asm volatile("s_waitcnt vmcnt(4)" ::: "memory"); }       \
        else          { asm volatile("s_waitcnt vmcnt(0)" ::: "memory"); }       \
        __builtin_amdgcn_s_barrier();                                            \
        if (kt_ + 2 < 24) { GEMM_STAGE((kt_ + 2) * 32, (kt_ + 2) % 3) }          \
        const int cur_ = kt_ % 3;                                                \
        short8 af[4], bfv[4];                                                    \
        _Pragma("unroll")                                                        \
        for (int m = 0; m < 4; ++m)                                              \
            af[m] = *(const short8*)((const char*)Abuf[cur_] + aoff[m]);         \
        _Pragma("unroll")                                                        \
        for (int n = 0; n < 4; ++n)                                              \
            bfv[n] = *(const short8*)((const char*)Bbuf[cur_] + boff[n]);        \
        _Pragma("unroll")                                                        \
        for (int m = 0; m < 4; ++m)                                              \
            _Pragma("unroll")                                                    \
            for (int n = 0; n < 4; ++n)                                          \
                acc[m][n] = __builtin_amdgcn_mfma_f32_16x16x32_bf16(             \
                    af[m], bfv[n], acc[m][n], 0, 0, 0);                          \
    }

// GEMM1: epilogue scatters q (scale*log2e folded), k (+rel), v (transposed)
__global__ __launch_bounds__(256) void gemm_qkv(
    const unsigned short* __restrict__ A,
    const unsigned short* __restrict__ Bt,
    const unsigned short* __restrict__ bias,
    const unsigned short* __restrict__ rel,
    unsigned short* __restrict__ q_ws,
    unsigned short* __restrict__ k_ws,
    unsigned short* __restrict__ v_ws)
{
    GEMM_PROLOG(A, Bt)
    const int gm0 = bm + wr * 64 + hi * 4;
    const float QSCALE = 0.125f * 1.44269504f;  // fold log2e: scores in log2 units
#pragma unroll
    for (int m = 0; m < 4; ++m) {
        int gm = gm0 + m * 16;
        int b_ = gm >> 10;
        int tt = gm & 1023;
#pragma unroll
        for (int n = 0; n < 4; ++n) {
            int col = bn + wc * 64 + n * 16 + lo;
            float bs = bf2f(bias[col]);
            if (col < 768) {
                int h = col >> 6, d = col & 63;
                size_t base = (((size_t)b_ * 12 + h) * 1024 + tt) * 64 + d;
#pragma unroll
                for (int j = 0; j < 4; ++j)
                    q_ws[base + (size_t)j * 64] = f2bf((acc[m][n][j] + bs) * QSCALE);
            } else if (col < 1536) {
                int h = (col - 768) >> 6, d = col & 63;
                size_t base = (((size_t)b_ * 12 + h) * 1024 + tt) * 64 + d;
#pragma unroll
                for (int j = 0; j < 4; ++j) {
                    int trow = tt + j;
                    float rv = (trow > 0) ? bf2f(rel[(size_t)(trow - 1) * 64 + d]) : 0.f;
                    k_ws[base + (size_t)j * 64] = f2bf(acc[m][n][j] + bs + rv);
                }
            } else {
                int h = (col - 1536) >> 6, d = col & 63;
                size_t vb = (((size_t)b_ * 12 + h) * 64 + d) * 1024 + tt;
                ushort4v pk;
#pragma unroll
                for (int j = 0; j < 4; ++j) pk[j] = f2bf(acc[m][n][j] + bs);
                *(ushort4v*)(v_ws + vb) = pk;
            }
        }
    }
}

// GEMM2: att @ wT_proj + b_proj -> out (dtype per flag)
__global__ __launch_bounds__(256) void gemm_proj(
    const unsigned short* __restrict__ A,
    const unsigned short* __restrict__ Bt,
    const unsigned short* __restrict__ bias,
    const int* __restrict__ flag,
    void* __restrict__ outv)
{
    GEMM_PROLOG(A, Bt)
    const int isbf = *flag;
    const int gm0 = bm + wr * 64 + hi * 4;
#pragma unroll
    for (int m = 0; m < 4; ++m) {
        int gm = gm0 + m * 16;
#pragma unroll
        for (int n = 0; n < 4; ++n) {
            int col = bn + wc * 64 + n * 16 + lo;
            float bs = bf2f(bias[col]);
#pragma unroll
            for (int j = 0; j < 4; ++j) {
                float v = acc[m][n][j] + bs;
                if (isbf)
                    ((unsigned short*)outv)[(size_t)(gm + j) * 768 + col] = f2bf(v);
                else
                    ((float*)outv)[(size_t)(gm + j) * 768 + col] = v;
            }
        }
    }
}

// ---------------- flash attention (v6: swapped QK^T, lane-local softmax) ------
__global__ __launch_bounds__(256) void attn_fused(
    const unsigned short* __restrict__ q_ws,
    const unsigned short* __restrict__ k_ws,
    const unsigned short* __restrict__ v_ws,
    unsigned short* __restrict__ att)
{
    __shared__ __align__(16) unsigned short Kbuf[2][64 * 64];
    __shared__ __align__(16) unsigned short Vbuf[2][64 * 64];
    __shared__ __align__(16) unsigned short Pbuf[4][16 * 64];
    const int t = threadIdx.x;
    const int wave = t >> 6, lane = t & 63;
    const int lo = lane & 15, hi = lane >> 4;
    const int gid = blockIdx.x;
    const int xcd = gid & 7;
    const int c = gid >> 3;            // 0..95
    const int bh = xcd * 12 + (c % 12);
    const int pairIdx = c / 12;        // 0..7
    const int b_ = bh / 12, h = bh % 12;
    const size_t base = (size_t)bh * (1024 * 64);
    const unsigned short* Kb = k_ws + base;
    const unsigned short* Vb = v_ws + base;
    const float DEFER_THR = 11.5f;     // ~8 nats in log2 units

    int L0 = t << 4, L1 = (t + 256) << 4;
    int S0 = L0 ^ (((L0 >> 7) & 7) << 4);
    int S1 = L1 ^ (((L1 >> 7) & 7) << 4);
    int r0 = S0 >> 7, o0 = (S0 & 127) >> 1;
    int r1 = S1 >> 7, o1 = (S1 & 127) >> 1;
    const int lof0 = (wave * 64) << 4;
    const int lof1 = (256 + wave * 64) << 4;

    int koff[4][2];
#pragma unroll
    for (int nt = 0; nt < 4; ++nt)
#pragma unroll
        for (int kc = 0; kc < 2; ++kc) {
            int P = ((nt * 16 + lo) << 7) + (kc << 6) + (hi << 4);
            koff[nt][kc] = P ^ (((P >> 7) & 7) << 4);
        }
    int poffR[2];
#pragma unroll
    for (int kc = 0; kc < 2; ++kc) {
        int P = (lo << 7) + (kc << 6) + (hi << 4);
        poffR[kc] = P ^ (((P >> 7) & 7) << 4);
    }
    int poffW[4][4];
#pragma unroll
    for (int nt = 0; nt < 4; ++nt)
#pragma unroll
        for (int j = 0; j < 4; ++j) {
            int P = (lo << 7) + ((nt * 16 + hi * 4 + j) << 1);
            poffW[nt][j] = P ^ ((lo & 7) << 4);
        }
    char* pb = (char*)&Pbuf[wave][0];

#pragma unroll 1
    for (int sel = 0; sel < 2; ++sel) {
        const int qt = sel ? pairIdx : (15 - pairIdx);
        const int q0w = qt * 64 + wave * 16;
        const int qrow = q0w + lo;     // this lane's q-row

        short8 qf[2];
#pragma unroll
        for (int kc = 0; kc < 2; ++kc)
            qf[kc] = *(const short8*)(q_ws + base +
                (size_t)(q0w + lo) * 64 + kc * 32 + hi * 8);

        f32x4 o[4];
        float mrun = -1e30f, lrun = 0.f;
#pragma unroll
        for (int nt = 0; nt < 4; ++nt) o[nt] = (f32x4){0.f, 0.f, 0.f, 0.f};

        if (sel) __syncthreads();
        glds16(Kb + (size_t)r0 * 64 + o0, (char*)Kbuf[0] + lof0);
        glds16(Kb + (size_t)r1 * 64 + o1, (char*)Kbuf[0] + lof1);
        glds16(Vb + (size_t)r0 * 1024 + o0, (char*)Vbuf[0] + lof0);
        glds16(Vb + (size_t)r1 * 1024 + o1, (char*)Vbuf[0] + lof1);

        int cur = 0;
        const int nkt = qt + 1;
        for (int kt = 0; kt < nkt; ++kt) {
            __syncthreads();  // staging of tile kt complete
            if (kt + 1 < nkt) {
                const int kn = (kt + 1) * 64;
                glds16(Kb + (size_t)(kn + r0) * 64 + o0, (char*)Kbuf[cur ^ 1] + lof0);
                glds16(Kb + (size_t)(kn + r1) * 64 + o1, (char*)Kbuf[cur ^ 1] + lof1);
                glds16(Vb + (size_t)r0 * 1024 + kn + o0, (char*)Vbuf[cur ^ 1] + lof0);
                glds16(Vb + (size_t)r1 * 1024 + kn + o1, (char*)Vbuf[cur ^ 1] + lof1);
            }
            const int kv0 = kt * 64;
            const char* Kc = (const char*)Kbuf[cur];
            const char* Vc = (const char*)Vbuf[cur];

            short8 kf[4][2];
#pragma unroll
            for (int nt = 0; nt < 4; ++nt)
#pragma unroll
                for (int kc = 0; kc < 2; ++kc)
                    kf[nt][kc] = *(const short8*)(Kc + koff[nt][kc]);
            // swapped: A=K, B=Q -> sc[nt] col=q(lo), rows=kv(hi*4+j)
            f32x4 sc[4];
            __builtin_amdgcn_s_setprio(1);
#pragma unroll
            for (int nt = 0; nt < 4; ++nt) {
                f32x4 z = (f32x4){0.f, 0.f, 0.f, 0.f};
                z = __builtin_amdgcn_mfma_f32_16x16x32_bf16(kf[nt][0], qf[0], z, 0, 0, 0);
                z = __builtin_amdgcn_mfma_f32_16x16x32_bf16(kf[nt][1], qf[1], z, 0, 0, 0);
                sc[nt] = z;
            }
            __builtin_amdgcn_s_setprio(0);
            if (kv0 + 63 > q0w) {
#pragma unroll
                for (int nt = 0; nt < 4; ++nt)
#pragma unroll
                    for (int j = 0; j < 4; ++j) {
                        int kc_ = kv0 + nt * 16 + hi * 4 + j;
                        if (kc_ > qrow) sc[nt][j] = -1e30f;
                    }
            }
            // lane-local row max (15 VALU) + 2 shfl across hi-groups
            float m0;
            {
                float a0 = fmaxf(fmaxf(sc[0][0], sc[0][1]), fmaxf(sc[0][2], sc[0][3]));
                float a1 = fmaxf(fmaxf(sc[1][0], sc[1][1]), fmaxf(sc[1][2], sc[1][3]));
                float a2 = fmaxf(fmaxf(sc[2][0], sc[2][1]), fmaxf(sc[2][2], sc[2][3]));
                float a3 = fmaxf(fmaxf(sc[3][0], sc[3][1]), fmaxf(sc[3][2], sc[3][3]));
                m0 = fmaxf(fmaxf(a0, a1), fmaxf(a2, a3));
            }
            m0 = fmaxf(m0, __shfl_xor(m0, 16));
            m0 = fmaxf(m0, __shfl_xor(m0, 32));
            // defer-max rescale
            if (__any(m0 > mrun + DEFER_THR)) {
                float nm = fmaxf(mrun, m0);
                float corr = __builtin_amdgcn_exp2f(mrun - nm);
                mrun = nm;
                lrun *= corr;
#pragma unroll
                for (int j = 0; j < 4; ++j) {
                    float cj = __shfl(corr, hi * 4 + j);
#pragma unroll
                    for (int nt = 0; nt < 4; ++nt) o[nt][j] *= cj;
                }
            }
            // exp2 + lane-local sum + 2 shfl
            float rs = 0.f;
#pragma unroll
            for (int nt = 0; nt < 4; ++nt)
#pragma unroll
                for (int j = 0; j < 4; ++j) {
                    float p = __builtin_amdgcn_exp2f(sc[nt][j] - mrun);
                    sc[nt][j] = p;
                    rs += p;
                }
            rs += __shfl_xor(rs, 16);
            rs += __shfl_xor(rs, 32);
            lrun += rs;
            // V fragments (hoisted)
            short8 vf[4][2];
#pragma unroll
            for (int nt = 0; nt < 4; ++nt)
#pragma unroll
                for (int kc2 = 0; kc2 < 2; ++kc2)
                    vf[nt][kc2] = *(const short8*)(Vc + koff[nt][kc2]);
            // P -> LDS (row = lo = q-row)
#pragma unroll
            for (int nt = 0; nt < 4; ++nt)
#pragma unroll
                for (int j = 0; j < 4; ++j)
                    *(unsigned short*)(pb + poffW[nt][j]) = f2bf(sc[nt][j]);
            // PV
#pragma unroll
            for (int kc2 = 0; kc2 < 2; ++kc2) {
                short8 pf = *(const short8*)(pb + poffR[kc2]);
                __builtin_amdgcn_s_setprio(1);
#pragma unroll
                for (int nt = 0; nt < 4; ++nt)
                    o[nt] = __builtin_amdgcn_mfma_f32_16x16x32_bf16(pf, vf[nt][kc2], o[nt], 0, 0, 0);
                __builtin_amdgcn_s_setprio(0);
            }
            cur ^= 1;
        }
        // epilogue: lrun for row hi*4+j lives at lane (hi*4+j)
#pragma unroll
        for (int j = 0; j < 4; ++j) {
            float lj = __shfl(lrun, hi * 4 + j);
            float inv = 1.f / lj;
            int tt = q0w + hi * 4 + j;
#pragma unroll
            for (int nt = 0; nt < 4; ++nt)
                att[((size_t)(b_ * 1024 + tt)) * 768 + h * 64 + nt * 16 + lo] =
                    f2bf(o[nt][j] * inv);
        }
    }
}

extern "C" void kernel_launch(void* const* d_in, const int* in_sizes, int n_in,
                              void* d_out, int out_size, void* d_ws, size_t ws_size,
                              hipStream_t stream) {
    const void* x      = d_in[0];
    const void* w_attn = d_in[1];
    const void* b_attn = d_in[2];
    const void* w_proj = d_in[3];
    const void* b_proj = d_in[4];
    const void* rel    = d_in[5];
    char* ws = (char*)d_ws;
    int*            flag = (int*)(ws + 0);
    unsigned short* wTa  = (unsigned short*)(ws + 4096);
    unsigned short* wTp  = (unsigned short*)(ws + 3543040);
    unsigned short* x_bf = (unsigned short*)(ws + 4722688);
    unsigned short* relb = (unsigned short*)(ws + 17305600);
    unsigned short* bab  = (unsigned short*)(ws + 17567616);
    unsigned short* bpb  = (unsigned short*)(ws + 17572224);
    unsigned short* q_ws = (unsigned short*)(ws + 17573760);
    unsigned short* k_ws = (unsigned short*)(ws + 30156672);
    unsigned short* v_ws = (unsigned short*)(ws + 42739584);
    unsigned short* att  = x_bf;  // reuse: x_bf dead after gemm_qkv

    detect_dtype<<<1, 256, 0, stream>>>((const unsigned int*)w_attn, flag);
    cast_x<<<6144, 256, 0, stream>>>(x, x_bf, flag);
    cast_small<<<524, 256, 0, stream>>>(rel, b_attn, b_proj, relb, bab, bpb, flag);
    transpose_w<<<dim3(36, 12), 256, 0, stream>>>(w_attn, wTa, 768, 2304, flag);
    transpose_w<<<dim3(12, 12), 256, 0, stream>>>(w_proj, wTp, 768, 768, flag);
    gemm_qkv<<<dim3(64, 18), 256, 0, stream>>>(x_bf, wTa, bab, relb, q_ws, k_ws, v_ws);
    attn_fused<<<768, 256, 0, stream>>>(q_ws, k_ws, v_ws, att);
    gemm_proj<<<dim3(64, 6), 256, 0, stream>>>(att, wTp, bpb, flag, (void*)d_out);
}